// Round 4
// baseline (7888.242 us; speedup 1.0000x reference)
//
#include <hip/hip_runtime.h>
#include <cmath>

#define BB 128
#define TT 256
#define DD 512
#define HH 256
#define G3 768   // 3*H

// ---- GEMM: C[m,n] = bias[n] + sum_k A[m,k]*W[n,k]; A (M,K), W (N,K) ------
__global__ __launch_bounds__(256) void gemm_abt(
    const float* __restrict__ A, const float* __restrict__ W,
    const float* __restrict__ bias, float* __restrict__ C,
    int M, int N, int K)
{
  __shared__ float sA[16][132];
  __shared__ float sB[16][132];
  const int tid = threadIdx.x;
  const int row0 = blockIdx.y * 128, col0 = blockIdx.x * 128;
  const int tx = tid & 15, ty = tid >> 4;
  float acc[8][8];
#pragma unroll
  for (int i = 0; i < 8; i++)
#pragma unroll
    for (int j = 0; j < 8; j++) acc[i][j] = 0.f;

  for (int k0 = 0; k0 < K; k0 += 16) {
    __syncthreads();
#pragma unroll
    for (int i = 0; i < 2; i++) {
      int q = tid + i * 256;
      int r = q >> 2, k4 = (q & 3) * 4;
      float4 av = *(const float4*)(A + (size_t)(row0 + r) * K + k0 + k4);
      sA[k4 + 0][r] = av.x; sA[k4 + 1][r] = av.y;
      sA[k4 + 2][r] = av.z; sA[k4 + 3][r] = av.w;
      float4 wv = make_float4(0.f, 0.f, 0.f, 0.f);
      if (col0 + r < N) wv = *(const float4*)(W + (size_t)(col0 + r) * K + k0 + k4);
      sB[k4 + 0][r] = wv.x; sB[k4 + 1][r] = wv.y;
      sB[k4 + 2][r] = wv.z; sB[k4 + 3][r] = wv.w;
    }
    __syncthreads();
#pragma unroll
    for (int k = 0; k < 16; k++) {
      float a0[8], b0[8];
      *(float4*)&a0[0] = *(const float4*)&sA[k][ty * 4];
      *(float4*)&a0[4] = *(const float4*)&sA[k][64 + ty * 4];
      *(float4*)&b0[0] = *(const float4*)&sB[k][tx * 4];
      *(float4*)&b0[4] = *(const float4*)&sB[k][64 + tx * 4];
#pragma unroll
      for (int i = 0; i < 8; i++)
#pragma unroll
        for (int j = 0; j < 8; j++) acc[i][j] += a0[i] * b0[j];
    }
  }
#pragma unroll
  for (int i = 0; i < 8; i++) {
    int r = row0 + ((i < 4) ? (ty * 4 + i) : (64 + ty * 4 + i - 4));
#pragma unroll
    for (int jq = 0; jq < 2; jq++) {
      int c = col0 + jq * 64 + tx * 4;
      if (c < N) {
        float4 v;
        v.x = acc[i][jq * 4 + 0] + bias[c + 0];
        v.y = acc[i][jq * 4 + 1] + bias[c + 1];
        v.z = acc[i][jq * 4 + 2] + bias[c + 2];
        v.w = acc[i][jq * 4 + 3] + bias[c + 3];
        *(float4*)(C + (size_t)r * N + c) = v;
      }
    }
  }
}

// -------- register-stationary GRU: 1 block per batch, block-local sync ----
// 1024 threads: thread (u = tid>>2, kc = tid&3) holds gate rows r,z,n of
// hidden unit u over k-slice [kc*64, kc*64+64) in 48 float4 VGPRs (192 regs).
// h (256 floats) lives in LDS; per step: broadcast ds_read_b128 + 192 FMA,
// butterfly __shfl_xor over the 4 kc lanes (same wave), lane kc==0 applies
// the gate nonlinearity and writes h + outp. Two __syncthreads per step.
// backward dir == iterate p = len-1..0 (input row == output row, no gather).
__global__ __launch_bounds__(1024, 4) void gru_reg_kernel(
    const float* __restrict__ xg, const float* __restrict__ w_hh,
    const float* __restrict__ bhh, const int* __restrict__ lengths,
    float* __restrict__ outp, int dir)
{
  const int tid = threadIdx.x;
  const int u = tid >> 2, kc = tid & 3;
  const int b = blockIdx.x;
  const int len = lengths[b];
  const int k0 = kc * 64;

  __shared__ float h_s[HH];
  if (tid < HH) h_s[tid] = 0.f;

  // one-time weight load into registers (rows g*256+u, cols k0..k0+63)
  float4 wr[16], wz[16], wn[16];
  {
    const float* pr = w_hh + (size_t)u * HH + k0;
    const float* pz = w_hh + (size_t)(HH + u) * HH + k0;
    const float* pn = w_hh + (size_t)(2 * HH + u) * HH + k0;
#pragma unroll
    for (int i = 0; i < 16; i++) {
      wr[i] = *(const float4*)(pr + 4 * i);
      wz[i] = *(const float4*)(pz + 4 * i);
      wn[i] = *(const float4*)(pn + 4 * i);
    }
  }
  const float br = bhh[u], bz = bhh[HH + u], bn = bhh[2 * HH + u];
  __syncthreads();

  // prefetch xg for t=0
  int p = dir ? (len - 1) : 0;
  const float* x0 = xg + ((size_t)b * TT + p) * G3;
  float xr_c = x0[u], xz_c = x0[HH + u], xn_c = x0[2 * HH + u];

  for (int t = 0; t < len; t++) {
    // prefetch next step's xg (hidden under the FMA chain)
    float xr_n = 0.f, xz_n = 0.f, xn_n = 0.f;
    if (t + 1 < len) {
      const int pnx = dir ? (len - 2 - t) : (t + 1);
      const float* xn_ptr = xg + ((size_t)b * TT + pnx) * G3;
      xr_n = xn_ptr[u]; xz_n = xn_ptr[HH + u]; xn_n = xn_ptr[2 * HH + u];
    }
    const float hold = h_s[u];
    float ar = 0.f, az = 0.f, an = 0.f;
#pragma unroll
    for (int i = 0; i < 16; i++) {
      float4 h4 = *(const float4*)&h_s[k0 + 4 * i];
      ar += h4.x * wr[i].x + h4.y * wr[i].y + h4.z * wr[i].z + h4.w * wr[i].w;
      az += h4.x * wz[i].x + h4.y * wz[i].y + h4.z * wz[i].z + h4.w * wz[i].w;
      an += h4.x * wn[i].x + h4.y * wn[i].y + h4.z * wn[i].z + h4.w * wn[i].w;
    }
    // butterfly reduce across the 4 kc lanes (adjacent lanes, same wave)
    ar += __shfl_xor(ar, 1); ar += __shfl_xor(ar, 2);
    az += __shfl_xor(az, 1); az += __shfl_xor(az, 2);
    an += __shfl_xor(an, 1); an += __shfl_xor(an, 2);
    __syncthreads();               // all h_s reads of this step complete
    if (kc == 0) {
      float r = 1.f / (1.f + expf(-(xr_c + ar + br)));
      float z = 1.f / (1.f + expf(-(xz_c + az + bz)));
      float n = tanhf(xn_c + r * (an + bn));
      float hn = (1.f - z) * n + z * hold;
      h_s[u] = hn;
      outp[((size_t)b * TT + p) * (2 * HH) + dir * HH + u] = hn;
    }
    __syncthreads();               // h_s ready for next step
    xr_c = xr_n; xz_c = xz_n; xn_c = xn_n;
    p = dir ? (p - 1) : (p + 1);
  }
}

// ------------- scores from hmid: relu, dot w2, +b2; mask t>=len ----------
__global__ __launch_bounds__(256) void score2_kernel(
    const float* __restrict__ hmid, const float* __restrict__ w2,
    const float* __restrict__ b2, const int* __restrict__ lengths,
    float* __restrict__ scores)
{
  const int wv = threadIdx.x >> 6, lane = threadIdx.x & 63;
  const int bt = blockIdx.x * 4 + wv;
  const int b = bt >> 8, t = bt & 255;
  float v = 0.f;
  if (t < lengths[b]) {
    float hv = fmaxf(hmid[(size_t)bt * 64 + lane], 0.f);
    v = hv * w2[lane];
#pragma unroll
    for (int o = 32; o > 0; o >>= 1) v += __shfl_down(v, o);
    v += b2[0];
  }
  if (lane == 0) scores[bt] = v;
}

// -------- softmax + top-3 + normalize + seq_feat, 1 block per batch ------
__global__ __launch_bounds__(256) void attn_kernel(
    const float* __restrict__ scores, const float* __restrict__ outp,
    const float* __restrict__ temp_ptr, const int* __restrict__ lengths,
    float* __restrict__ seq_feat)
{
  const int b = blockIdx.x;
  const int t = threadIdx.x;
  const int len = lengths[b];
  float temp = fminf(fmaxf(temp_ptr[0], 0.001f), 10.0f);
  __shared__ float red[256];
  __shared__ int redi[256];
  __shared__ float topv[3]; __shared__ int topi[3];
  __shared__ float vn[3]; __shared__ float vsum_s;
  const bool valid = t < len;
  float logit = valid ? scores[b * TT + t] / temp : -INFINITY;
  red[t] = logit; __syncthreads();
  for (int s = 128; s > 0; s >>= 1) {
    if (t < s) red[t] = fmaxf(red[t], red[t + s]);
    __syncthreads();
  }
  float mx = red[0]; __syncthreads();
  float e = valid ? expf(logit - mx) : 0.f;
  red[t] = e; __syncthreads();
  for (int s = 128; s > 0; s >>= 1) {
    if (t < s) red[t] += red[t + s];
    __syncthreads();
  }
  float sum = red[0]; __syncthreads();
  float myp = e / sum;
  for (int it = 0; it < 3; it++) {
    red[t] = myp; redi[t] = t; __syncthreads();
    for (int s = 128; s > 0; s >>= 1) {
      if (t < s) {
        float v2 = red[t + s]; int i2 = redi[t + s];
        if (v2 > red[t] || (v2 == red[t] && i2 < redi[t])) { red[t] = v2; redi[t] = i2; }
      }
      __syncthreads();
    }
    if (t == 0) { topv[it] = red[0]; topi[it] = redi[0]; }
    __syncthreads();
    if (t == topi[it]) myp = -1.f;
    __syncthreads();
  }
  if (t == 0) {
    int k_act = len < 3 ? len : 3;
    float vsum = 0.f;
    for (int jj = 0; jj < 3; jj++) if (jj < k_act) vsum += topv[jj];
    vsum_s = vsum;
    float denom = fmaxf(vsum, 1e-8f);
    for (int jj = 0; jj < 3; jj++) vn[jj] = (jj < k_act) ? topv[jj] / denom : 0.f;
  }
  __syncthreads();
  if (vsum_s > 1e-8f) {
    for (int hh = t; hh < 2 * HH; hh += 256) {
      float s = 0.f;
      for (int jj = 0; jj < 3; jj++)
        s += vn[jj] * outp[((size_t)b * TT + topi[jj]) * (2 * HH) + hh];
      seq_feat[b * 2 * HH + hh] = s;
    }
  } else {
    float inv = 1.f / ((float)len + 1e-8f);
    for (int hh = t; hh < 2 * HH; hh += 256) {
      float s = 0.f;
      for (int tt2 = 0; tt2 < len; tt2++)
        s += outp[((size_t)b * TT + tt2) * (2 * HH) + hh];
      seq_feat[b * 2 * HH + hh] = s * inv;
    }
  }
}

// ------------------- final heads: (B,11) then (B,10) ---------------------
__global__ __launch_bounds__(256) void head_kernel(
    const float* __restrict__ seq_feat,
    const float* __restrict__ w_tens, const float* __restrict__ b_tens,
    const float* __restrict__ w_ones, const float* __restrict__ b_ones,
    float* __restrict__ d_out)
{
  const int b = blockIdx.x;
  const int lane = threadIdx.x & 63, wv = threadIdx.x >> 6;
  const float* sf = seq_feat + (size_t)b * 2 * HH;
  for (int o = wv; o < 21; o += 4) {
    const float* wr = (o < 11) ? (w_tens + (size_t)o * 2 * HH)
                               : (w_ones + (size_t)(o - 11) * 2 * HH);
    float s = 0.f;
    for (int e2 = lane; e2 < 2 * HH; e2 += 64) s += sf[e2] * wr[e2];
#pragma unroll
    for (int off2 = 32; off2 > 0; off2 >>= 1) s += __shfl_down(s, off2);
    if (lane == 0) {
      if (o < 11) d_out[b * 11 + o] = s + b_tens[o];
      else d_out[BB * 11 + b * 10 + (o - 11)] = s + b_ones[o - 11];
    }
  }
}

extern "C" void kernel_launch(void* const* d_in, const int* in_sizes, int n_in,
                              void* d_out, int out_size, void* d_ws, size_t ws_size,
                              hipStream_t stream)
{
  const float* feats       = (const float*)d_in[0];
  const int*   lengths     = (const int*)d_in[1];
  const float* temperature = (const float*)d_in[2];
  const float* w_ih_f = (const float*)d_in[3];
  const float* w_hh_f = (const float*)d_in[4];
  const float* b_ih_f = (const float*)d_in[5];
  const float* b_hh_f = (const float*)d_in[6];
  const float* w_ih_b = (const float*)d_in[7];
  const float* w_hh_b = (const float*)d_in[8];
  const float* b_ih_b = (const float*)d_in[9];
  const float* b_hh_b = (const float*)d_in[10];
  const float* w1 = (const float*)d_in[11];
  const float* b1 = (const float*)d_in[12];
  const float* w2 = (const float*)d_in[13];
  const float* b2 = (const float*)d_in[14];
  const float* w_tens = (const float*)d_in[15];
  const float* b_tens = (const float*)d_in[16];
  const float* w_ones = (const float*)d_in[17];
  const float* b_ones = (const float*)d_in[18];
  float* out = (float*)d_out;

  // ---- workspace layout (peak ~168 MB; xg reused per dir, tail aliased) --
  char* ws = (char*)d_ws;
  size_t off = 0;
  auto alloc = [&](size_t nfloats) {
    float* p = (float*)(ws + off);
    off += nfloats * sizeof(float);
    return p;
  };
  float* xg   = alloc((size_t)BB * TT * G3);      // 100.7 MB
  float* outp = alloc((size_t)BB * TT * 2 * HH);  // 67.1 MB
  float* hmid     = xg;                           // aliases (xg dead after GRUs)
  float* scores   = xg + (size_t)BB * TT * 64;
  float* seq_feat = scores + (size_t)BB * TT;

  // forward direction
  gemm_abt<<<dim3(6, 256), 256, 0, stream>>>(feats, w_ih_f, b_ih_f, xg, BB * TT, G3, DD);
  gru_reg_kernel<<<BB, 1024, 0, stream>>>(xg, w_hh_f, b_hh_f, lengths, outp, 0);
  // backward direction (reuses xg)
  gemm_abt<<<dim3(6, 256), 256, 0, stream>>>(feats, w_ih_b, b_ih_b, xg, BB * TT, G3, DD);
  gru_reg_kernel<<<BB, 1024, 0, stream>>>(xg, w_hh_b, b_hh_b, lengths, outp, 1);
  // score MLP + attention + heads
  gemm_abt<<<dim3(1, 256), 256, 0, stream>>>(outp, w1, b1, hmid, BB * TT, 64, 2 * HH);
  score2_kernel<<<BB * TT / 4, 256, 0, stream>>>(hmid, w2, b2, lengths, scores);
  attn_kernel<<<BB, 256, 0, stream>>>(scores, outp, temperature, lengths, seq_feat);
  head_kernel<<<BB, 256, 0, stream>>>(seq_feat, w_tens, b_tens, w_ones, b_ones, out);
}

// Round 5
// 3566.935 us; speedup vs baseline: 2.2115x; 2.2115x over previous
//
#include <hip/hip_runtime.h>
#include <cmath>

#define BB 128
#define TT 256
#define DD 512
#define HH 256
#define G3 768   // 3*H

// ---- GEMM: C[m,n] = bias[n] + sum_k A[m,k]*W[n,k]; A (M,K), W (N,K) ------
__global__ __launch_bounds__(256) void gemm_abt(
    const float* __restrict__ A, const float* __restrict__ W,
    const float* __restrict__ bias, float* __restrict__ C,
    int M, int N, int K)
{
  __shared__ float sA[16][132];
  __shared__ float sB[16][132];
  const int tid = threadIdx.x;
  const int row0 = blockIdx.y * 128, col0 = blockIdx.x * 128;
  const int tx = tid & 15, ty = tid >> 4;
  float acc[8][8];
#pragma unroll
  for (int i = 0; i < 8; i++)
#pragma unroll
    for (int j = 0; j < 8; j++) acc[i][j] = 0.f;

  for (int k0 = 0; k0 < K; k0 += 16) {
    __syncthreads();
#pragma unroll
    for (int i = 0; i < 2; i++) {
      int q = tid + i * 256;
      int r = q >> 2, k4 = (q & 3) * 4;
      float4 av = *(const float4*)(A + (size_t)(row0 + r) * K + k0 + k4);
      sA[k4 + 0][r] = av.x; sA[k4 + 1][r] = av.y;
      sA[k4 + 2][r] = av.z; sA[k4 + 3][r] = av.w;
      float4 wv = make_float4(0.f, 0.f, 0.f, 0.f);
      if (col0 + r < N) wv = *(const float4*)(W + (size_t)(col0 + r) * K + k0 + k4);
      sB[k4 + 0][r] = wv.x; sB[k4 + 1][r] = wv.y;
      sB[k4 + 2][r] = wv.z; sB[k4 + 3][r] = wv.w;
    }
    __syncthreads();
#pragma unroll
    for (int k = 0; k < 16; k++) {
      float a0[8], b0[8];
      *(float4*)&a0[0] = *(const float4*)&sA[k][ty * 4];
      *(float4*)&a0[4] = *(const float4*)&sA[k][64 + ty * 4];
      *(float4*)&b0[0] = *(const float4*)&sB[k][tx * 4];
      *(float4*)&b0[4] = *(const float4*)&sB[k][64 + tx * 4];
#pragma unroll
      for (int i = 0; i < 8; i++)
#pragma unroll
        for (int j = 0; j < 8; j++) acc[i][j] += a0[i] * b0[j];
    }
  }
#pragma unroll
  for (int i = 0; i < 8; i++) {
    int r = row0 + ((i < 4) ? (ty * 4 + i) : (64 + ty * 4 + i - 4));
#pragma unroll
    for (int jq = 0; jq < 2; jq++) {
      int c = col0 + jq * 64 + tx * 4;
      if (c < N) {
        float4 v;
        v.x = acc[i][jq * 4 + 0] + bias[c + 0];
        v.y = acc[i][jq * 4 + 1] + bias[c + 1];
        v.z = acc[i][jq * 4 + 2] + bias[c + 2];
        v.w = acc[i][jq * 4 + 3] + bias[c + 3];
        *(float4*)(C + (size_t)r * N + c) = v;
      }
    }
  }
}

// ---- register-stationary GRU, 2 blocks per batch, pairwise handshake ----
// 256 blocks x 512 threads. Block (batch = bx>>1, half = bx&1) owns units
// [half*128, half*128+128). Thread (ul = tid>>2, kc = tid&3) holds gate rows
// r,z,n of unit u = half*128+ul over k-slice [kc*64, kc*64+64): 48 float4 =
// 192 VGPRs. 512 thr = 8 waves @ <=256 VGPR -> 2 waves/SIMD -> 1 block/CU,
// all 256 blocks co-resident (spin-safe). Per step: matvec from LDS h_s,
// shfl_xor reduce over kc, kc==0 applies gates, halves exchange 128 floats
// via parity-double-buffered Hx + agent-scope flag (round-3-proven pattern).
__global__ __launch_bounds__(512, 2) void gru_pair_kernel(
    const float* __restrict__ xg, const float* __restrict__ w_hh,
    const float* __restrict__ bhh, const int* __restrict__ lengths,
    float* __restrict__ outp, float* __restrict__ Hx,   // [2][BB][HH]
    unsigned* __restrict__ flags, int dir)              // [BB][16], 64B/batch
{
  const int tid = threadIdx.x;
  const int batch = blockIdx.x >> 1, half = blockIdx.x & 1;
  const int ul = tid >> 2, kc = tid & 3;
  const int u = half * 128 + ul;
  const int po = (1 - half) * 128;          // partner's unit range base
  const int len = lengths[batch];
  const int k0 = kc * 64;
  unsigned* myflag = flags + batch * 16 + half;
  unsigned* pflag  = flags + batch * 16 + (1 - half);

  __shared__ float h_s[HH];
  if (tid < HH) h_s[tid] = 0.f;

  // one-time weight load into registers (rows g*HH+u, cols k0..k0+63)
  float4 wr[16], wz[16], wn[16];
  {
    const float* pr = w_hh + (size_t)u * HH + k0;
    const float* pz = w_hh + (size_t)(HH + u) * HH + k0;
    const float* pn = w_hh + (size_t)(2 * HH + u) * HH + k0;
#pragma unroll
    for (int i = 0; i < 16; i++) {
      wr[i] = *(const float4*)(pr + 4 * i);
      wz[i] = *(const float4*)(pz + 4 * i);
      wn[i] = *(const float4*)(pn + 4 * i);
    }
  }
  const float br = bhh[u], bz = bhh[HH + u], bn = bhh[2 * HH + u];
  __syncthreads();

  // xg prefetch for t=0 (only kc==0 lanes consume it)
  int p = dir ? (len - 1) : 0;
  float xr_c = 0.f, xz_c = 0.f, xn_c = 0.f;
  if (kc == 0) {
    const float* x0 = xg + ((size_t)batch * TT + p) * G3;
    xr_c = x0[u]; xz_c = x0[HH + u]; xn_c = x0[2 * HH + u];
  }

  for (int t = 0; t < len; t++) {
    // prefetch next step's xg (hidden under the FMA chain)
    float xr_n = 0.f, xz_n = 0.f, xn_n = 0.f;
    if (kc == 0 && t + 1 < len) {
      const int pnx = dir ? (len - 2 - t) : (t + 1);
      const float* xp = xg + ((size_t)batch * TT + pnx) * G3;
      xr_n = xp[u]; xz_n = xp[HH + u]; xn_n = xp[2 * HH + u];
    }
    const float hold = h_s[u];
    float ar = 0.f, az = 0.f, an = 0.f;
#pragma unroll
    for (int i = 0; i < 16; i++) {
      float4 h4 = *(const float4*)&h_s[k0 + 4 * i];
      ar += h4.x * wr[i].x + h4.y * wr[i].y + h4.z * wr[i].z + h4.w * wr[i].w;
      az += h4.x * wz[i].x + h4.y * wz[i].y + h4.z * wz[i].z + h4.w * wz[i].w;
      an += h4.x * wn[i].x + h4.y * wn[i].y + h4.z * wn[i].z + h4.w * wn[i].w;
    }
    // butterfly reduce across the 4 kc lanes (same wave, adjacent lanes)
    ar += __shfl_xor(ar, 1); ar += __shfl_xor(ar, 2);
    az += __shfl_xor(az, 1); az += __shfl_xor(az, 2);
    an += __shfl_xor(an, 1); an += __shfl_xor(an, 2);
    __syncthreads();               // all h_s reads of this step complete

    float* Hpar = Hx + (size_t)((t + 1) & 1) * BB * HH + (size_t)batch * HH;
    if (kc == 0) {
      float r = 1.f / (1.f + expf(-(xr_c + ar + br)));
      float z = 1.f / (1.f + expf(-(xz_c + az + bz)));
      float n = tanhf(xn_c + r * (an + bn));
      float hn = (1.f - z) * n + z * hold;
      h_s[u] = hn;
      Hpar[u] = hn;                // own half -> exchange buffer
      outp[((size_t)batch * TT + p) * (2 * HH) + dir * HH + u] = hn;
    }
    __syncthreads();               // Hx writes drained (vmcnt(0) per thread)
    if (tid == 0) {
      __hip_atomic_fetch_add(myflag, 1u, __ATOMIC_RELEASE, __HIP_MEMORY_SCOPE_AGENT);
      while (__hip_atomic_load(pflag, __ATOMIC_ACQUIRE, __HIP_MEMORY_SCOPE_AGENT)
             < (unsigned)(t + 1))
        __builtin_amdgcn_s_sleep(1);
    }
    __syncthreads();               // partner data visible (L1/L2 inv'd)
    if (tid < 128) h_s[po + tid] = Hpar[po + tid];
    __syncthreads();               // h_s complete for next step
    xr_c = xr_n; xz_c = xz_n; xn_c = xn_n;
    p = dir ? (p - 1) : (p + 1);
  }
}

// ------------- scores from hmid: relu, dot w2, +b2; mask t>=len ----------
__global__ __launch_bounds__(256) void score2_kernel(
    const float* __restrict__ hmid, const float* __restrict__ w2,
    const float* __restrict__ b2, const int* __restrict__ lengths,
    float* __restrict__ scores)
{
  const int wv = threadIdx.x >> 6, lane = threadIdx.x & 63;
  const int bt = blockIdx.x * 4 + wv;
  const int b = bt >> 8, t = bt & 255;
  float v = 0.f;
  if (t < lengths[b]) {
    float hv = fmaxf(hmid[(size_t)bt * 64 + lane], 0.f);
    v = hv * w2[lane];
#pragma unroll
    for (int o = 32; o > 0; o >>= 1) v += __shfl_down(v, o);
    v += b2[0];
  }
  if (lane == 0) scores[bt] = v;
}

// -------- softmax + top-3 + normalize + seq_feat, 1 block per batch ------
__global__ __launch_bounds__(256) void attn_kernel(
    const float* __restrict__ scores, const float* __restrict__ outp,
    const float* __restrict__ temp_ptr, const int* __restrict__ lengths,
    float* __restrict__ seq_feat)
{
  const int b = blockIdx.x;
  const int t = threadIdx.x;
  const int len = lengths[b];
  float temp = fminf(fmaxf(temp_ptr[0], 0.001f), 10.0f);
  __shared__ float red[256];
  __shared__ int redi[256];
  __shared__ float topv[3]; __shared__ int topi[3];
  __shared__ float vn[3]; __shared__ float vsum_s;
  const bool valid = t < len;
  float logit = valid ? scores[b * TT + t] / temp : -INFINITY;
  red[t] = logit; __syncthreads();
  for (int s = 128; s > 0; s >>= 1) {
    if (t < s) red[t] = fmaxf(red[t], red[t + s]);
    __syncthreads();
  }
  float mx = red[0]; __syncthreads();
  float e = valid ? expf(logit - mx) : 0.f;
  red[t] = e; __syncthreads();
  for (int s = 128; s > 0; s >>= 1) {
    if (t < s) red[t] += red[t + s];
    __syncthreads();
  }
  float sum = red[0]; __syncthreads();
  float myp = e / sum;
  for (int it = 0; it < 3; it++) {
    red[t] = myp; redi[t] = t; __syncthreads();
    for (int s = 128; s > 0; s >>= 1) {
      if (t < s) {
        float v2 = red[t + s]; int i2 = redi[t + s];
        if (v2 > red[t] || (v2 == red[t] && i2 < redi[t])) { red[t] = v2; redi[t] = i2; }
      }
      __syncthreads();
    }
    if (t == 0) { topv[it] = red[0]; topi[it] = redi[0]; }
    __syncthreads();
    if (t == topi[it]) myp = -1.f;
    __syncthreads();
  }
  if (t == 0) {
    int k_act = len < 3 ? len : 3;
    float vsum = 0.f;
    for (int jj = 0; jj < 3; jj++) if (jj < k_act) vsum += topv[jj];
    vsum_s = vsum;
    float denom = fmaxf(vsum, 1e-8f);
    for (int jj = 0; jj < 3; jj++) vn[jj] = (jj < k_act) ? topv[jj] / denom : 0.f;
  }
  __syncthreads();
  if (vsum_s > 1e-8f) {
    for (int hh = t; hh < 2 * HH; hh += 256) {
      float s = 0.f;
      for (int jj = 0; jj < 3; jj++)
        s += vn[jj] * outp[((size_t)b * TT + topi[jj]) * (2 * HH) + hh];
      seq_feat[b * 2 * HH + hh] = s;
    }
  } else {
    float inv = 1.f / ((float)len + 1e-8f);
    for (int hh = t; hh < 2 * HH; hh += 256) {
      float s = 0.f;
      for (int tt2 = 0; tt2 < len; tt2++)
        s += outp[((size_t)b * TT + tt2) * (2 * HH) + hh];
      seq_feat[b * 2 * HH + hh] = s * inv;
    }
  }
}

// ------------------- final heads: (B,11) then (B,10) ---------------------
__global__ __launch_bounds__(256) void head_kernel(
    const float* __restrict__ seq_feat,
    const float* __restrict__ w_tens, const float* __restrict__ b_tens,
    const float* __restrict__ w_ones, const float* __restrict__ b_ones,
    float* __restrict__ d_out)
{
  const int b = blockIdx.x;
  const int lane = threadIdx.x & 63, wv = threadIdx.x >> 6;
  const float* sf = seq_feat + (size_t)b * 2 * HH;
  for (int o = wv; o < 21; o += 4) {
    const float* wr = (o < 11) ? (w_tens + (size_t)o * 2 * HH)
                               : (w_ones + (size_t)(o - 11) * 2 * HH);
    float s = 0.f;
    for (int e2 = lane; e2 < 2 * HH; e2 += 64) s += sf[e2] * wr[e2];
#pragma unroll
    for (int off2 = 32; off2 > 0; off2 >>= 1) s += __shfl_down(s, off2);
    if (lane == 0) {
      if (o < 11) d_out[b * 11 + o] = s + b_tens[o];
      else d_out[BB * 11 + b * 10 + (o - 11)] = s + b_ones[o - 11];
    }
  }
}

extern "C" void kernel_launch(void* const* d_in, const int* in_sizes, int n_in,
                              void* d_out, int out_size, void* d_ws, size_t ws_size,
                              hipStream_t stream)
{
  const float* feats       = (const float*)d_in[0];
  const int*   lengths     = (const int*)d_in[1];
  const float* temperature = (const float*)d_in[2];
  const float* w_ih_f = (const float*)d_in[3];
  const float* w_hh_f = (const float*)d_in[4];
  const float* b_ih_f = (const float*)d_in[5];
  const float* b_hh_f = (const float*)d_in[6];
  const float* w_ih_b = (const float*)d_in[7];
  const float* w_hh_b = (const float*)d_in[8];
  const float* b_ih_b = (const float*)d_in[9];
  const float* b_hh_b = (const float*)d_in[10];
  const float* w1 = (const float*)d_in[11];
  const float* b1 = (const float*)d_in[12];
  const float* w2 = (const float*)d_in[13];
  const float* b2 = (const float*)d_in[14];
  const float* w_tens = (const float*)d_in[15];
  const float* b_tens = (const float*)d_in[16];
  const float* w_ones = (const float*)d_in[17];
  const float* b_ones = (const float*)d_in[18];
  float* out = (float*)d_out;

  // ---- workspace layout (peak ~169 MB; xg reused per dir, tail aliased) --
  char* ws = (char*)d_ws;
  size_t off = 0;
  auto alloc = [&](size_t nfloats) {
    float* p = (float*)(ws + off);
    off += nfloats * sizeof(float);
    return p;
  };
  float*    xg    = alloc((size_t)BB * TT * G3);      // 100.7 MB
  float*    outp  = alloc((size_t)BB * TT * 2 * HH);  // 67.1 MB
  float*    Hx    = alloc((size_t)2 * BB * HH);       // 256 KB
  unsigned* flags = (unsigned*)(ws + off); off += BB * 16 * sizeof(unsigned); // 8 KB
  float* hmid     = xg;                               // aliases (xg dead after GRUs)
  float* scores   = xg + (size_t)BB * TT * 64;
  float* seq_feat = scores + (size_t)BB * TT;

  // forward direction
  hipMemsetAsync(flags, 0, BB * 16 * sizeof(unsigned), stream);
  gemm_abt<<<dim3(6, 256), 256, 0, stream>>>(feats, w_ih_f, b_ih_f, xg, BB * TT, G3, DD);
  gru_pair_kernel<<<2 * BB, 512, 0, stream>>>(xg, w_hh_f, b_hh_f, lengths, outp, Hx, flags, 0);
  // backward direction (reuses xg; fresh flags)
  hipMemsetAsync(flags, 0, BB * 16 * sizeof(unsigned), stream);
  gemm_abt<<<dim3(6, 256), 256, 0, stream>>>(feats, w_ih_b, b_ih_b, xg, BB * TT, G3, DD);
  gru_pair_kernel<<<2 * BB, 512, 0, stream>>>(xg, w_hh_b, b_hh_b, lengths, outp, Hx, flags, 1);
  // score MLP + attention + heads
  gemm_abt<<<dim3(1, 256), 256, 0, stream>>>(outp, w1, b1, hmid, BB * TT, 64, 2 * HH);
  score2_kernel<<<BB * TT / 4, 256, 0, stream>>>(hmid, w2, b2, lengths, scores);
  attn_kernel<<<BB, 256, 0, stream>>>(scores, outp, temperature, lengths, seq_feat);
  head_kernel<<<BB, 256, 0, stream>>>(seq_feat, w_tens, b_tens, w_ones, b_ones, out);
}

// Round 6
// 3191.157 us; speedup vs baseline: 2.4719x; 1.1178x over previous
//
#include <hip/hip_runtime.h>
#include <cmath>

#define BB 128
#define TT 256
#define DD 512
#define HH 256
#define G3 768   // 3*H

// ---- GEMM: C[m,n] = bias[n] + sum_k A[m,k]*W[n,k]; A (M,K), W (N,K) ------
__global__ __launch_bounds__(256) void gemm_abt(
    const float* __restrict__ A, const float* __restrict__ W,
    const float* __restrict__ bias, float* __restrict__ C,
    int M, int N, int K)
{
  __shared__ float sA[16][132];
  __shared__ float sB[16][132];
  const int tid = threadIdx.x;
  const int row0 = blockIdx.y * 128, col0 = blockIdx.x * 128;
  const int tx = tid & 15, ty = tid >> 4;
  float acc[8][8];
#pragma unroll
  for (int i = 0; i < 8; i++)
#pragma unroll
    for (int j = 0; j < 8; j++) acc[i][j] = 0.f;

  for (int k0 = 0; k0 < K; k0 += 16) {
    __syncthreads();
#pragma unroll
    for (int i = 0; i < 2; i++) {
      int q = tid + i * 256;
      int r = q >> 2, k4 = (q & 3) * 4;
      float4 av = *(const float4*)(A + (size_t)(row0 + r) * K + k0 + k4);
      sA[k4 + 0][r] = av.x; sA[k4 + 1][r] = av.y;
      sA[k4 + 2][r] = av.z; sA[k4 + 3][r] = av.w;
      float4 wv = make_float4(0.f, 0.f, 0.f, 0.f);
      if (col0 + r < N) wv = *(const float4*)(W + (size_t)(col0 + r) * K + k0 + k4);
      sB[k4 + 0][r] = wv.x; sB[k4 + 1][r] = wv.y;
      sB[k4 + 2][r] = wv.z; sB[k4 + 3][r] = wv.w;
    }
    __syncthreads();
#pragma unroll
    for (int k = 0; k < 16; k++) {
      float a0[8], b0[8];
      *(float4*)&a0[0] = *(const float4*)&sA[k][ty * 4];
      *(float4*)&a0[4] = *(const float4*)&sA[k][64 + ty * 4];
      *(float4*)&b0[0] = *(const float4*)&sB[k][tx * 4];
      *(float4*)&b0[4] = *(const float4*)&sB[k][64 + tx * 4];
#pragma unroll
      for (int i = 0; i < 8; i++)
#pragma unroll
        for (int j = 0; j < 8; j++) acc[i][j] += a0[i] * b0[j];
    }
  }
#pragma unroll
  for (int i = 0; i < 8; i++) {
    int r = row0 + ((i < 4) ? (ty * 4 + i) : (64 + ty * 4 + i - 4));
#pragma unroll
    for (int jq = 0; jq < 2; jq++) {
      int c = col0 + jq * 64 + tx * 4;
      if (c < N) {
        float4 v;
        v.x = acc[i][jq * 4 + 0] + bias[c + 0];
        v.y = acc[i][jq * 4 + 1] + bias[c + 1];
        v.z = acc[i][jq * 4 + 2] + bias[c + 2];
        v.w = acc[i][jq * 4 + 3] + bias[c + 3];
        *(float4*)(C + (size_t)r * N + c) = v;
      }
    }
  }
}

// ---- register-stationary GRU, 2 blocks per batch, pairwise handshake ----
// 256 blocks x 256 threads, __launch_bounds__(256,1) -> 512 VGPR/lane budget
// so the 384-float weight slice is GENUINELY register-resident (round-5's
// 512thr/256-reg config demoted weights to per-step L2 reloads -> L2-bound).
// Block (batch = bx&127, half = bx>>7) owns units [half*128, half*128+128);
// partner pairing (bx, bx+128) lands both halves on the same XCD under
// round-robin placement (bx%8) -> handshake resolves in shared L2 (heuristic
// only; agent-scope ops keep it correct under any placement).
// Thread (ul = tid>>1, kc = tid&1): gate rows r,z,n of unit u = half*128+ul
// over k-slice [kc*128, kc*128+128) = 96 float4. kc reduce = 1 shfl_xor.
// 2-way LDS bank aliasing on h_s reads is free (m136).
__global__ __launch_bounds__(256, 1) void gru_pair_kernel(
    const float* __restrict__ xg, const float* __restrict__ w_hh,
    const float* __restrict__ bhh, const int* __restrict__ lengths,
    float* __restrict__ outp, float* __restrict__ Hx,   // [2][BB][HH]
    unsigned* __restrict__ flags, int dir)              // [BB][16], 64B/batch
{
  const int tid = threadIdx.x;
  const int batch = blockIdx.x & 127, half = blockIdx.x >> 7;
  const int ul = tid >> 1, kc = tid & 1;
  const int u = half * 128 + ul;
  const int po = (1 - half) * 128;          // partner's unit range base
  const int len = lengths[batch];
  const int k0 = kc * 128;
  unsigned* myflag = flags + batch * 16 + half;
  unsigned* pflag  = flags + batch * 16 + (1 - half);

  __shared__ float h_s[HH];
  if (tid < HH) h_s[tid] = 0.f;

  // one-time weight load into registers (rows g*HH+u, cols k0..k0+127)
  float4 wr[32], wz[32], wn[32];
  {
    const float* pr = w_hh + (size_t)u * HH + k0;
    const float* pz = w_hh + (size_t)(HH + u) * HH + k0;
    const float* pn = w_hh + (size_t)(2 * HH + u) * HH + k0;
#pragma unroll
    for (int i = 0; i < 32; i++) {
      wr[i] = *(const float4*)(pr + 4 * i);
      wz[i] = *(const float4*)(pz + 4 * i);
      wn[i] = *(const float4*)(pn + 4 * i);
    }
  }
  const float br = bhh[u], bz = bhh[HH + u], bn = bhh[2 * HH + u];
  __syncthreads();

  // xg prefetch for t=0 (only kc==0 lanes consume it)
  int p = dir ? (len - 1) : 0;
  float xr_c = 0.f, xz_c = 0.f, xn_c = 0.f;
  if (kc == 0) {
    const float* x0 = xg + ((size_t)batch * TT + p) * G3;
    xr_c = x0[u]; xz_c = x0[HH + u]; xn_c = x0[2 * HH + u];
  }

  for (int t = 0; t < len; t++) {
    // prefetch next step's xg (hidden under the FMA chain)
    float xr_n = 0.f, xz_n = 0.f, xn_n = 0.f;
    if (kc == 0 && t + 1 < len) {
      const int pnx = dir ? (len - 2 - t) : (t + 1);
      const float* xp = xg + ((size_t)batch * TT + pnx) * G3;
      xr_n = xp[u]; xz_n = xp[HH + u]; xn_n = xp[2 * HH + u];
    }
    const float hold = h_s[u];
    float ar = 0.f, az = 0.f, an = 0.f;
#pragma unroll
    for (int i = 0; i < 32; i++) {
      float4 h4 = *(const float4*)&h_s[k0 + 4 * i];
      ar += h4.x * wr[i].x + h4.y * wr[i].y + h4.z * wr[i].z + h4.w * wr[i].w;
      az += h4.x * wz[i].x + h4.y * wz[i].y + h4.z * wz[i].z + h4.w * wz[i].w;
      an += h4.x * wn[i].x + h4.y * wn[i].y + h4.z * wn[i].z + h4.w * wn[i].w;
    }
    // reduce across the 2 kc lanes (adjacent lanes, same wave)
    ar += __shfl_xor(ar, 1);
    az += __shfl_xor(az, 1);
    an += __shfl_xor(an, 1);
    __syncthreads();               // all h_s reads of this step complete

    float* Hpar = Hx + (size_t)((t + 1) & 1) * BB * HH + (size_t)batch * HH;
    if (kc == 0) {
      float r = 1.f / (1.f + expf(-(xr_c + ar + br)));
      float z = 1.f / (1.f + expf(-(xz_c + az + bz)));
      float n = tanhf(xn_c + r * (an + bn));
      float hn = (1.f - z) * n + z * hold;
      h_s[u] = hn;
      Hpar[u] = hn;                // own half -> exchange buffer
      outp[((size_t)batch * TT + p) * (2 * HH) + dir * HH + u] = hn;
    }
    __syncthreads();               // Hx writes drained (vmcnt(0) per thread)
    if (tid == 0) {
      __hip_atomic_fetch_add(myflag, 1u, __ATOMIC_RELEASE, __HIP_MEMORY_SCOPE_AGENT);
      // relaxed poll (no per-poll cache invalidate), then one acquire fence
      while (__hip_atomic_load(pflag, __ATOMIC_RELAXED, __HIP_MEMORY_SCOPE_AGENT)
             < (unsigned)(t + 1))
        __builtin_amdgcn_s_sleep(1);
      __builtin_amdgcn_fence(__ATOMIC_ACQUIRE, "agent");
    }
    __syncthreads();               // partner data visible to whole block
    if (tid < 128) h_s[po + tid] = Hpar[po + tid];
    __syncthreads();               // h_s complete for next step
    xr_c = xr_n; xz_c = xz_n; xn_c = xn_n;
    p = dir ? (p - 1) : (p + 1);
  }
}

// ------------- scores from hmid: relu, dot w2, +b2; mask t>=len ----------
__global__ __launch_bounds__(256) void score2_kernel(
    const float* __restrict__ hmid, const float* __restrict__ w2,
    const float* __restrict__ b2, const int* __restrict__ lengths,
    float* __restrict__ scores)
{
  const int wv = threadIdx.x >> 6, lane = threadIdx.x & 63;
  const int bt = blockIdx.x * 4 + wv;
  const int b = bt >> 8, t = bt & 255;
  float v = 0.f;
  if (t < lengths[b]) {
    float hv = fmaxf(hmid[(size_t)bt * 64 + lane], 0.f);
    v = hv * w2[lane];
#pragma unroll
    for (int o = 32; o > 0; o >>= 1) v += __shfl_down(v, o);
    v += b2[0];
  }
  if (lane == 0) scores[bt] = v;
}

// -------- softmax + top-3 + normalize + seq_feat, 1 block per batch ------
__global__ __launch_bounds__(256) void attn_kernel(
    const float* __restrict__ scores, const float* __restrict__ outp,
    const float* __restrict__ temp_ptr, const int* __restrict__ lengths,
    float* __restrict__ seq_feat)
{
  const int b = blockIdx.x;
  const int t = threadIdx.x;
  const int len = lengths[b];
  float temp = fminf(fmaxf(temp_ptr[0], 0.001f), 10.0f);
  __shared__ float red[256];
  __shared__ int redi[256];
  __shared__ float topv[3]; __shared__ int topi[3];
  __shared__ float vn[3]; __shared__ float vsum_s;
  const bool valid = t < len;
  float logit = valid ? scores[b * TT + t] / temp : -INFINITY;
  red[t] = logit; __syncthreads();
  for (int s = 128; s > 0; s >>= 1) {
    if (t < s) red[t] = fmaxf(red[t], red[t + s]);
    __syncthreads();
  }
  float mx = red[0]; __syncthreads();
  float e = valid ? expf(logit - mx) : 0.f;
  red[t] = e; __syncthreads();
  for (int s = 128; s > 0; s >>= 1) {
    if (t < s) red[t] += red[t + s];
    __syncthreads();
  }
  float sum = red[0]; __syncthreads();
  float myp = e / sum;
  for (int it = 0; it < 3; it++) {
    red[t] = myp; redi[t] = t; __syncthreads();
    for (int s = 128; s > 0; s >>= 1) {
      if (t < s) {
        float v2 = red[t + s]; int i2 = redi[t + s];
        if (v2 > red[t] || (v2 == red[t] && i2 < redi[t])) { red[t] = v2; redi[t] = i2; }
      }
      __syncthreads();
    }
    if (t == 0) { topv[it] = red[0]; topi[it] = redi[0]; }
    __syncthreads();
    if (t == topi[it]) myp = -1.f;
    __syncthreads();
  }
  if (t == 0) {
    int k_act = len < 3 ? len : 3;
    float vsum = 0.f;
    for (int jj = 0; jj < 3; jj++) if (jj < k_act) vsum += topv[jj];
    vsum_s = vsum;
    float denom = fmaxf(vsum, 1e-8f);
    for (int jj = 0; jj < 3; jj++) vn[jj] = (jj < k_act) ? topv[jj] / denom : 0.f;
  }
  __syncthreads();
  if (vsum_s > 1e-8f) {
    for (int hh = t; hh < 2 * HH; hh += 256) {
      float s = 0.f;
      for (int jj = 0; jj < 3; jj++)
        s += vn[jj] * outp[((size_t)b * TT + topi[jj]) * (2 * HH) + hh];
      seq_feat[b * 2 * HH + hh] = s;
    }
  } else {
    float inv = 1.f / ((float)len + 1e-8f);
    for (int hh = t; hh < 2 * HH; hh += 256) {
      float s = 0.f;
      for (int tt2 = 0; tt2 < len; tt2++)
        s += outp[((size_t)b * TT + tt2) * (2 * HH) + hh];
      seq_feat[b * 2 * HH + hh] = s * inv;
    }
  }
}

// ------------------- final heads: (B,11) then (B,10) ---------------------
__global__ __launch_bounds__(256) void head_kernel(
    const float* __restrict__ seq_feat,
    const float* __restrict__ w_tens, const float* __restrict__ b_tens,
    const float* __restrict__ w_ones, const float* __restrict__ b_ones,
    float* __restrict__ d_out)
{
  const int b = blockIdx.x;
  const int lane = threadIdx.x & 63, wv = threadIdx.x >> 6;
  const float* sf = seq_feat + (size_t)b * 2 * HH;
  for (int o = wv; o < 21; o += 4) {
    const float* wr = (o < 11) ? (w_tens + (size_t)o * 2 * HH)
                               : (w_ones + (size_t)(o - 11) * 2 * HH);
    float s = 0.f;
    for (int e2 = lane; e2 < 2 * HH; e2 += 64) s += sf[e2] * wr[e2];
#pragma unroll
    for (int off2 = 32; off2 > 0; off2 >>= 1) s += __shfl_down(s, off2);
    if (lane == 0) {
      if (o < 11) d_out[b * 11 + o] = s + b_tens[o];
      else d_out[BB * 11 + b * 10 + (o - 11)] = s + b_ones[o - 11];
    }
  }
}

extern "C" void kernel_launch(void* const* d_in, const int* in_sizes, int n_in,
                              void* d_out, int out_size, void* d_ws, size_t ws_size,
                              hipStream_t stream)
{
  const float* feats       = (const float*)d_in[0];
  const int*   lengths     = (const int*)d_in[1];
  const float* temperature = (const float*)d_in[2];
  const float* w_ih_f = (const float*)d_in[3];
  const float* w_hh_f = (const float*)d_in[4];
  const float* b_ih_f = (const float*)d_in[5];
  const float* b_hh_f = (const float*)d_in[6];
  const float* w_ih_b = (const float*)d_in[7];
  const float* w_hh_b = (const float*)d_in[8];
  const float* b_ih_b = (const float*)d_in[9];
  const float* b_hh_b = (const float*)d_in[10];
  const float* w1 = (const float*)d_in[11];
  const float* b1 = (const float*)d_in[12];
  const float* w2 = (const float*)d_in[13];
  const float* b2 = (const float*)d_in[14];
  const float* w_tens = (const float*)d_in[15];
  const float* b_tens = (const float*)d_in[16];
  const float* w_ones = (const float*)d_in[17];
  const float* b_ones = (const float*)d_in[18];
  float* out = (float*)d_out;

  // ---- workspace layout (peak ~169 MB; xg reused per dir, tail aliased) --
  char* ws = (char*)d_ws;
  size_t off = 0;
  auto alloc = [&](size_t nfloats) {
    float* p = (float*)(ws + off);
    off += nfloats * sizeof(float);
    return p;
  };
  float*    xg    = alloc((size_t)BB * TT * G3);      // 100.7 MB
  float*    outp  = alloc((size_t)BB * TT * 2 * HH);  // 67.1 MB
  float*    Hx    = alloc((size_t)2 * BB * HH);       // 256 KB
  unsigned* flags = (unsigned*)(ws + off); off += BB * 16 * sizeof(unsigned); // 8 KB
  float* hmid     = xg;                               // aliases (xg dead after GRUs)
  float* scores   = xg + (size_t)BB * TT * 64;
  float* seq_feat = scores + (size_t)BB * TT;

  // forward direction
  hipMemsetAsync(flags, 0, BB * 16 * sizeof(unsigned), stream);
  gemm_abt<<<dim3(6, 256), 256, 0, stream>>>(feats, w_ih_f, b_ih_f, xg, BB * TT, G3, DD);
  gru_pair_kernel<<<2 * BB, 256, 0, stream>>>(xg, w_hh_f, b_hh_f, lengths, outp, Hx, flags, 0);
  // backward direction (reuses xg; fresh flags)
  hipMemsetAsync(flags, 0, BB * 16 * sizeof(unsigned), stream);
  gemm_abt<<<dim3(6, 256), 256, 0, stream>>>(feats, w_ih_b, b_ih_b, xg, BB * TT, G3, DD);
  gru_pair_kernel<<<2 * BB, 256, 0, stream>>>(xg, w_hh_b, b_hh_b, lengths, outp, Hx, flags, 1);
  // score MLP + attention + heads
  gemm_abt<<<dim3(1, 256), 256, 0, stream>>>(outp, w1, b1, hmid, BB * TT, 64, 2 * HH);
  score2_kernel<<<BB * TT / 4, 256, 0, stream>>>(hmid, w2, b2, lengths, scores);
  attn_kernel<<<BB, 256, 0, stream>>>(scores, outp, temperature, lengths, seq_feat);
  head_kernel<<<BB, 256, 0, stream>>>(seq_feat, w_tens, b_tens, w_ones, b_ones, out);
}

// Round 7
// 2442.961 us; speedup vs baseline: 3.2290x; 1.3063x over previous
//
#include <hip/hip_runtime.h>
#include <cmath>

#define BB 128
#define TT 256
#define DD 512
#define HH 256
#define G3 768   // 3*H

// ---- GEMM: C[m,n] = bias[n] + sum_k A[m,k]*W[n,k]; A (M,K), W (N,K) ------
__global__ __launch_bounds__(256) void gemm_abt(
    const float* __restrict__ A, const float* __restrict__ W,
    const float* __restrict__ bias, float* __restrict__ C,
    int M, int N, int K)
{
  __shared__ float sA[16][132];
  __shared__ float sB[16][132];
  const int tid = threadIdx.x;
  const int row0 = blockIdx.y * 128, col0 = blockIdx.x * 128;
  const int tx = tid & 15, ty = tid >> 4;
  float acc[8][8];
#pragma unroll
  for (int i = 0; i < 8; i++)
#pragma unroll
    for (int j = 0; j < 8; j++) acc[i][j] = 0.f;

  for (int k0 = 0; k0 < K; k0 += 16) {
    __syncthreads();
#pragma unroll
    for (int i = 0; i < 2; i++) {
      int q = tid + i * 256;
      int r = q >> 2, k4 = (q & 3) * 4;
      float4 av = *(const float4*)(A + (size_t)(row0 + r) * K + k0 + k4);
      sA[k4 + 0][r] = av.x; sA[k4 + 1][r] = av.y;
      sA[k4 + 2][r] = av.z; sA[k4 + 3][r] = av.w;
      float4 wv = make_float4(0.f, 0.f, 0.f, 0.f);
      if (col0 + r < N) wv = *(const float4*)(W + (size_t)(col0 + r) * K + k0 + k4);
      sB[k4 + 0][r] = wv.x; sB[k4 + 1][r] = wv.y;
      sB[k4 + 2][r] = wv.z; sB[k4 + 3][r] = wv.w;
    }
    __syncthreads();
#pragma unroll
    for (int k = 0; k < 16; k++) {
      float a0[8], b0[8];
      *(float4*)&a0[0] = *(const float4*)&sA[k][ty * 4];
      *(float4*)&a0[4] = *(const float4*)&sA[k][64 + ty * 4];
      *(float4*)&b0[0] = *(const float4*)&sB[k][tx * 4];
      *(float4*)&b0[4] = *(const float4*)&sB[k][64 + tx * 4];
#pragma unroll
      for (int i = 0; i < 8; i++)
#pragma unroll
        for (int j = 0; j < 8; j++) acc[i][j] += a0[i] * b0[j];
    }
  }
#pragma unroll
  for (int i = 0; i < 8; i++) {
    int r = row0 + ((i < 4) ? (ty * 4 + i) : (64 + ty * 4 + i - 4));
#pragma unroll
    for (int jq = 0; jq < 2; jq++) {
      int c = col0 + jq * 64 + tx * 4;
      if (c < N) {
        float4 v;
        v.x = acc[i][jq * 4 + 0] + bias[c + 0];
        v.y = acc[i][jq * 4 + 1] + bias[c + 1];
        v.z = acc[i][jq * 4 + 2] + bias[c + 2];
        v.w = acc[i][jq * 4 + 3] + bias[c + 3];
        *(float4*)(C + (size_t)r * N + c) = v;
      }
    }
  }
}

// ---- register-stationary GRU, 2 blocks per batch, pairwise handshake ----
// 256 blocks x 256 threads, __launch_bounds__(256,1) -> 512 VGPR/lane budget.
// r6 lesson: the allocator happily REMATERIALIZES loop-invariant weight
// loads (VGPR_Count=216) -> per-step reloads, which the per-step agent
// acquire fence forced out to L3 (L2 invalidated every step). Fixes:
//  (a) empty asm "+v" barriers make the 384 weight floats opaque ->
//      allocator must keep them live in the unified VGPR/AGPR file;
//  (b) handshake uses RELAXED cache-bypassing agent atomics for data+flag
//      (ordering via __syncthreads' vmcnt(0) drain) -> no wbl2/inv per step,
//      L2 keeps the xg stream.
// Thread (ul = tid>>1, kc = tid&1): gate rows r,z,n of unit u = half*128+ul
// over k-slice [kc*128, kc*128+128) = 96 float4 = 384 VGPRs.
// Pairing (bx, bx+128): same XCD under round-robin placement (heuristic).
__global__ __launch_bounds__(256, 1) void gru_pair_kernel(
    const float* __restrict__ xg, const float* __restrict__ w_hh,
    const float* __restrict__ bhh, const int* __restrict__ lengths,
    float* __restrict__ outp, float* __restrict__ Hx,   // [2][BB][HH]
    unsigned* __restrict__ flags, int dir)              // [BB][16], 64B/batch
{
  const int tid = threadIdx.x;
  const int batch = blockIdx.x & 127, half = blockIdx.x >> 7;
  const int ul = tid >> 1, kc = tid & 1;
  const int u = half * 128 + ul;
  const int po = (1 - half) * 128;          // partner's unit range base
  const int len = lengths[batch];
  const int k0 = kc * 128;
  unsigned* myflag = flags + batch * 16 + half;
  unsigned* pflag  = flags + batch * 16 + (1 - half);

  __shared__ float h_s[HH];
  if (tid < HH) h_s[tid] = 0.f;

  // one-time weight load; asm barriers pin the values in registers
  float4 wr[32], wz[32], wn[32];
  {
    const float* pr = w_hh + (size_t)u * HH + k0;
    const float* pz = w_hh + (size_t)(HH + u) * HH + k0;
    const float* pn = w_hh + (size_t)(2 * HH + u) * HH + k0;
#pragma unroll
    for (int i = 0; i < 32; i++) {
      wr[i] = *(const float4*)(pr + 4 * i);
      wz[i] = *(const float4*)(pz + 4 * i);
      wn[i] = *(const float4*)(pn + 4 * i);
    }
#pragma unroll
    for (int i = 0; i < 32; i++) {
      asm volatile("" : "+v"(wr[i].x), "+v"(wr[i].y), "+v"(wr[i].z), "+v"(wr[i].w));
      asm volatile("" : "+v"(wz[i].x), "+v"(wz[i].y), "+v"(wz[i].z), "+v"(wz[i].w));
      asm volatile("" : "+v"(wn[i].x), "+v"(wn[i].y), "+v"(wn[i].z), "+v"(wn[i].w));
    }
  }
  const float br = bhh[u], bz = bhh[HH + u], bn = bhh[2 * HH + u];
  __syncthreads();

  // xg prefetch for t=0 (only kc==0 lanes consume it)
  int p = dir ? (len - 1) : 0;
  float xr_c = 0.f, xz_c = 0.f, xn_c = 0.f;
  if (kc == 0) {
    const float* x0 = xg + ((size_t)batch * TT + p) * G3;
    xr_c = x0[u]; xz_c = x0[HH + u]; xn_c = x0[2 * HH + u];
  }

  for (int t = 0; t < len; t++) {
    // prefetch next step's xg (hidden under the FMA chain)
    float xr_n = 0.f, xz_n = 0.f, xn_n = 0.f;
    if (kc == 0 && t + 1 < len) {
      const int pnx = dir ? (len - 2 - t) : (t + 1);
      const float* xp = xg + ((size_t)batch * TT + pnx) * G3;
      xr_n = xp[u]; xz_n = xp[HH + u]; xn_n = xp[2 * HH + u];
    }
    const float hold = h_s[u];
    float ar = 0.f, az = 0.f, an = 0.f;
#pragma unroll
    for (int i = 0; i < 32; i++) {
      float4 h4 = *(const float4*)&h_s[k0 + 4 * i];
      ar += h4.x * wr[i].x + h4.y * wr[i].y + h4.z * wr[i].z + h4.w * wr[i].w;
      az += h4.x * wz[i].x + h4.y * wz[i].y + h4.z * wz[i].z + h4.w * wz[i].w;
      an += h4.x * wn[i].x + h4.y * wn[i].y + h4.z * wn[i].z + h4.w * wn[i].w;
    }
    // reduce across the 2 kc lanes (adjacent lanes, same wave)
    ar += __shfl_xor(ar, 1);
    az += __shfl_xor(az, 1);
    an += __shfl_xor(an, 1);
    __syncthreads();               // all h_s reads of this step complete

    float* Hpar = Hx + (size_t)((t + 1) & 1) * BB * HH + (size_t)batch * HH;
    if (kc == 0) {
      float r = 1.f / (1.f + expf(-(xr_c + ar + br)));
      float z = 1.f / (1.f + expf(-(xz_c + az + bz)));
      float n = tanhf(xn_c + r * (an + bn));
      float hn = (1.f - z) * n + z * hold;
      h_s[u] = hn;
      // own half -> exchange buffer, cache-bypassing (agent-coherent)
      __hip_atomic_store(&Hpar[u], hn, __ATOMIC_RELAXED, __HIP_MEMORY_SCOPE_AGENT);
      outp[((size_t)batch * TT + p) * (2 * HH) + dir * HH + u] = hn;
    }
    __syncthreads();               // vmcnt(0): data stores globally visible
    if (tid == 0) {
      __hip_atomic_fetch_add(myflag, 1u, __ATOMIC_RELAXED, __HIP_MEMORY_SCOPE_AGENT);
      while (__hip_atomic_load(pflag, __ATOMIC_RELAXED, __HIP_MEMORY_SCOPE_AGENT)
             < (unsigned)(t + 1))
        __builtin_amdgcn_s_sleep(1);
    }
    __syncthreads();               // whole block past partner's signal
    if (tid < 128) {               // partner half via cache-bypassing loads
      h_s[po + tid] = __hip_atomic_load(&Hpar[po + tid], __ATOMIC_RELAXED,
                                        __HIP_MEMORY_SCOPE_AGENT);
    }
    __syncthreads();               // h_s complete for next step
    xr_c = xr_n; xz_c = xz_n; xn_c = xn_n;
    p = dir ? (p - 1) : (p + 1);
  }
}

// ------------- scores from hmid: relu, dot w2, +b2; mask t>=len ----------
__global__ __launch_bounds__(256) void score2_kernel(
    const float* __restrict__ hmid, const float* __restrict__ w2,
    const float* __restrict__ b2, const int* __restrict__ lengths,
    float* __restrict__ scores)
{
  const int wv = threadIdx.x >> 6, lane = threadIdx.x & 63;
  const int bt = blockIdx.x * 4 + wv;
  const int b = bt >> 8, t = bt & 255;
  float v = 0.f;
  if (t < lengths[b]) {
    float hv = fmaxf(hmid[(size_t)bt * 64 + lane], 0.f);
    v = hv * w2[lane];
#pragma unroll
    for (int o = 32; o > 0; o >>= 1) v += __shfl_down(v, o);
    v += b2[0];
  }
  if (lane == 0) scores[bt] = v;
}

// -------- softmax + top-3 + normalize + seq_feat, 1 block per batch ------
__global__ __launch_bounds__(256) void attn_kernel(
    const float* __restrict__ scores, const float* __restrict__ outp,
    const float* __restrict__ temp_ptr, const int* __restrict__ lengths,
    float* __restrict__ seq_feat)
{
  const int b = blockIdx.x;
  const int t = threadIdx.x;
  const int len = lengths[b];
  float temp = fminf(fmaxf(temp_ptr[0], 0.001f), 10.0f);
  __shared__ float red[256];
  __shared__ int redi[256];
  __shared__ float topv[3]; __shared__ int topi[3];
  __shared__ float vn[3]; __shared__ float vsum_s;
  const bool valid = t < len;
  float logit = valid ? scores[b * TT + t] / temp : -INFINITY;
  red[t] = logit; __syncthreads();
  for (int s = 128; s > 0; s >>= 1) {
    if (t < s) red[t] = fmaxf(red[t], red[t + s]);
    __syncthreads();
  }
  float mx = red[0]; __syncthreads();
  float e = valid ? expf(logit - mx) : 0.f;
  red[t] = e; __syncthreads();
  for (int s = 128; s > 0; s >>= 1) {
    if (t < s) red[t] += red[t + s];
    __syncthreads();
  }
  float sum = red[0]; __syncthreads();
  float myp = e / sum;
  for (int it = 0; it < 3; it++) {
    red[t] = myp; redi[t] = t; __syncthreads();
    for (int s = 128; s > 0; s >>= 1) {
      if (t < s) {
        float v2 = red[t + s]; int i2 = redi[t + s];
        if (v2 > red[t] || (v2 == red[t] && i2 < redi[t])) { red[t] = v2; redi[t] = i2; }
      }
      __syncthreads();
    }
    if (t == 0) { topv[it] = red[0]; topi[it] = redi[0]; }
    __syncthreads();
    if (t == topi[it]) myp = -1.f;
    __syncthreads();
  }
  if (t == 0) {
    int k_act = len < 3 ? len : 3;
    float vsum = 0.f;
    for (int jj = 0; jj < 3; jj++) if (jj < k_act) vsum += topv[jj];
    vsum_s = vsum;
    float denom = fmaxf(vsum, 1e-8f);
    for (int jj = 0; jj < 3; jj++) vn[jj] = (jj < k_act) ? topv[jj] / denom : 0.f;
  }
  __syncthreads();
  if (vsum_s > 1e-8f) {
    for (int hh = t; hh < 2 * HH; hh += 256) {
      float s = 0.f;
      for (int jj = 0; jj < 3; jj++)
        s += vn[jj] * outp[((size_t)b * TT + topi[jj]) * (2 * HH) + hh];
      seq_feat[b * 2 * HH + hh] = s;
    }
  } else {
    float inv = 1.f / ((float)len + 1e-8f);
    for (int hh = t; hh < 2 * HH; hh += 256) {
      float s = 0.f;
      for (int tt2 = 0; tt2 < len; tt2++)
        s += outp[((size_t)b * TT + tt2) * (2 * HH) + hh];
      seq_feat[b * 2 * HH + hh] = s * inv;
    }
  }
}

// ------------------- final heads: (B,11) then (B,10) ---------------------
__global__ __launch_bounds__(256) void head_kernel(
    const float* __restrict__ seq_feat,
    const float* __restrict__ w_tens, const float* __restrict__ b_tens,
    const float* __restrict__ w_ones, const float* __restrict__ b_ones,
    float* __restrict__ d_out)
{
  const int b = blockIdx.x;
  const int lane = threadIdx.x & 63, wv = threadIdx.x >> 6;
  const float* sf = seq_feat + (size_t)b * 2 * HH;
  for (int o = wv; o < 21; o += 4) {
    const float* wr = (o < 11) ? (w_tens + (size_t)o * 2 * HH)
                               : (w_ones + (size_t)(o - 11) * 2 * HH);
    float s = 0.f;
    for (int e2 = lane; e2 < 2 * HH; e2 += 64) s += sf[e2] * wr[e2];
#pragma unroll
    for (int off2 = 32; off2 > 0; off2 >>= 1) s += __shfl_down(s, off2);
    if (lane == 0) {
      if (o < 11) d_out[b * 11 + o] = s + b_tens[o];
      else d_out[BB * 11 + b * 10 + (o - 11)] = s + b_ones[o - 11];
    }
  }
}

extern "C" void kernel_launch(void* const* d_in, const int* in_sizes, int n_in,
                              void* d_out, int out_size, void* d_ws, size_t ws_size,
                              hipStream_t stream)
{
  const float* feats       = (const float*)d_in[0];
  const int*   lengths     = (const int*)d_in[1];
  const float* temperature = (const float*)d_in[2];
  const float* w_ih_f = (const float*)d_in[3];
  const float* w_hh_f = (const float*)d_in[4];
  const float* b_ih_f = (const float*)d_in[5];
  const float* b_hh_f = (const float*)d_in[6];
  const float* w_ih_b = (const float*)d_in[7];
  const float* w_hh_b = (const float*)d_in[8];
  const float* b_ih_b = (const float*)d_in[9];
  const float* b_hh_b = (const float*)d_in[10];
  const float* w1 = (const float*)d_in[11];
  const float* b1 = (const float*)d_in[12];
  const float* w2 = (const float*)d_in[13];
  const float* b2 = (const float*)d_in[14];
  const float* w_tens = (const float*)d_in[15];
  const float* b_tens = (const float*)d_in[16];
  const float* w_ones = (const float*)d_in[17];
  const float* b_ones = (const float*)d_in[18];
  float* out = (float*)d_out;

  // ---- workspace layout (peak ~169 MB; xg reused per dir, tail aliased) --
  char* ws = (char*)d_ws;
  size_t off = 0;
  auto alloc = [&](size_t nfloats) {
    float* p = (float*)(ws + off);
    off += nfloats * sizeof(float);
    return p;
  };
  float*    xg    = alloc((size_t)BB * TT * G3);      // 100.7 MB
  float*    outp  = alloc((size_t)BB * TT * 2 * HH);  // 67.1 MB
  float*    Hx    = alloc((size_t)2 * BB * HH);       // 256 KB
  unsigned* flags = (unsigned*)(ws + off); off += BB * 16 * sizeof(unsigned); // 8 KB
  float* hmid     = xg;                               // aliases (xg dead after GRUs)
  float* scores   = xg + (size_t)BB * TT * 64;
  float* seq_feat = scores + (size_t)BB * TT;

  // forward direction
  hipMemsetAsync(flags, 0, BB * 16 * sizeof(unsigned), stream);
  gemm_abt<<<dim3(6, 256), 256, 0, stream>>>(feats, w_ih_f, b_ih_f, xg, BB * TT, G3, DD);
  gru_pair_kernel<<<2 * BB, 256, 0, stream>>>(xg, w_hh_f, b_hh_f, lengths, outp, Hx, flags, 0);
  // backward direction (reuses xg; fresh flags)
  hipMemsetAsync(flags, 0, BB * 16 * sizeof(unsigned), stream);
  gemm_abt<<<dim3(6, 256), 256, 0, stream>>>(feats, w_ih_b, b_ih_b, xg, BB * TT, G3, DD);
  gru_pair_kernel<<<2 * BB, 256, 0, stream>>>(xg, w_hh_b, b_hh_b, lengths, outp, Hx, flags, 1);
  // score MLP + attention + heads
  gemm_abt<<<dim3(1, 256), 256, 0, stream>>>(outp, w1, b1, hmid, BB * TT, 64, 2 * HH);
  score2_kernel<<<BB * TT / 4, 256, 0, stream>>>(hmid, w2, b2, lengths, scores);
  attn_kernel<<<BB, 256, 0, stream>>>(scores, outp, temperature, lengths, seq_feat);
  head_kernel<<<BB, 256, 0, stream>>>(seq_feat, w_tens, b_tens, w_ones, b_ones, out);
}

// Round 8
// 2166.821 us; speedup vs baseline: 3.6405x; 1.1274x over previous
//
#include <hip/hip_runtime.h>
#include <cmath>

#define BB 128
#define TT 256
#define DD 512
#define HH 256
#define G3 768   // 3*H

// ---- GEMM: C[m,n] = bias[n] + sum_k A[m,k]*W[n,k]; A (M,K), W (N,K) ------
__global__ __launch_bounds__(256) void gemm_abt(
    const float* __restrict__ A, const float* __restrict__ W,
    const float* __restrict__ bias, float* __restrict__ C,
    int M, int N, int K)
{
  __shared__ float sA[16][132];
  __shared__ float sB[16][132];
  const int tid = threadIdx.x;
  const int row0 = blockIdx.y * 128, col0 = blockIdx.x * 128;
  const int tx = tid & 15, ty = tid >> 4;
  float acc[8][8];
#pragma unroll
  for (int i = 0; i < 8; i++)
#pragma unroll
    for (int j = 0; j < 8; j++) acc[i][j] = 0.f;

  for (int k0 = 0; k0 < K; k0 += 16) {
    __syncthreads();
#pragma unroll
    for (int i = 0; i < 2; i++) {
      int q = tid + i * 256;
      int r = q >> 2, k4 = (q & 3) * 4;
      float4 av = *(const float4*)(A + (size_t)(row0 + r) * K + k0 + k4);
      sA[k4 + 0][r] = av.x; sA[k4 + 1][r] = av.y;
      sA[k4 + 2][r] = av.z; sA[k4 + 3][r] = av.w;
      float4 wv = make_float4(0.f, 0.f, 0.f, 0.f);
      if (col0 + r < N) wv = *(const float4*)(W + (size_t)(col0 + r) * K + k0 + k4);
      sB[k4 + 0][r] = wv.x; sB[k4 + 1][r] = wv.y;
      sB[k4 + 2][r] = wv.z; sB[k4 + 3][r] = wv.w;
    }
    __syncthreads();
#pragma unroll
    for (int k = 0; k < 16; k++) {
      float a0[8], b0[8];
      *(float4*)&a0[0] = *(const float4*)&sA[k][ty * 4];
      *(float4*)&a0[4] = *(const float4*)&sA[k][64 + ty * 4];
      *(float4*)&b0[0] = *(const float4*)&sB[k][tx * 4];
      *(float4*)&b0[4] = *(const float4*)&sB[k][64 + tx * 4];
#pragma unroll
      for (int i = 0; i < 8; i++)
#pragma unroll
        for (int j = 0; j < 8; j++) acc[i][j] += a0[i] * b0[j];
    }
  }
#pragma unroll
  for (int i = 0; i < 8; i++) {
    int r = row0 + ((i < 4) ? (ty * 4 + i) : (64 + ty * 4 + i - 4));
#pragma unroll
    for (int jq = 0; jq < 2; jq++) {
      int c = col0 + jq * 64 + tx * 4;
      if (c < N) {
        float4 v;
        v.x = acc[i][jq * 4 + 0] + bias[c + 0];
        v.y = acc[i][jq * 4 + 1] + bias[c + 1];
        v.z = acc[i][jq * 4 + 2] + bias[c + 2];
        v.w = acc[i][jq * 4 + 3] + bias[c + 3];
        *(float4*)(C + (size_t)r * N + c) = v;
      }
    }
  }
}

// ---- register-stationary GRU, 2 blocks per batch, TAGGED-VALUE exchange --
// 256 blocks x 256 threads, __launch_bounds__(256,1). Weights pinned in the
// unified VGPR/AGPR file via asm "+v" barriers (r7-proven: 820us, VALU 20%).
// r8 change: the 3-roundtrip flag handshake (store-drain -> fetch_add ->
// tid0 poll -> 128 loads) becomes ONE roundtrip: each exchanged h value is a
// 64-bit word (tag<<32)|float_bits, tag=(dir<<9)|(t+1), stored relaxed
// agent-scope (single-copy atomic: tag+data arrive together). Reader lane
// polls ITS OWN slot until the tag matches. No flags, no parity buffer
// (tags disambiguate steps and directions), no per-launch memset; ws
// re-poison 0xAA can never equal a valid tag. 2 barriers/step (was 3).
// Thread (ul = tid>>1, kc = tid&1): gate rows r,z,n of unit u = half*128+ul
// over k-slice [kc*128, kc*128+128) = 96 float4. Pairing (bx, bx+128).
__global__ __launch_bounds__(256, 1) void gru_pair_kernel(
    const float* __restrict__ xg, const float* __restrict__ w_hh,
    const float* __restrict__ bhh, const int* __restrict__ lengths,
    float* __restrict__ outp,
    unsigned long long* __restrict__ Hx,   // [BB][HH] tagged slots
    int dir)
{
  const int tid = threadIdx.x;
  const int batch = blockIdx.x & 127, half = blockIdx.x >> 7;
  const int ul = tid >> 1, kc = tid & 1;
  const int u = half * 128 + ul;
  const int po = (1 - half) * 128;          // partner's unit range base
  const int len = lengths[batch];
  const int k0 = kc * 128;
  unsigned long long* slots = Hx + (size_t)batch * HH;

  __shared__ float h_s[HH];
  if (tid < HH) h_s[tid] = 0.f;

  // one-time weight load; asm barriers pin the values in registers
  float4 wr[32], wz[32], wn[32];
  {
    const float* pr = w_hh + (size_t)u * HH + k0;
    const float* pz = w_hh + (size_t)(HH + u) * HH + k0;
    const float* pn = w_hh + (size_t)(2 * HH + u) * HH + k0;
#pragma unroll
    for (int i = 0; i < 32; i++) {
      wr[i] = *(const float4*)(pr + 4 * i);
      wz[i] = *(const float4*)(pz + 4 * i);
      wn[i] = *(const float4*)(pn + 4 * i);
    }
#pragma unroll
    for (int i = 0; i < 32; i++) {
      asm volatile("" : "+v"(wr[i].x), "+v"(wr[i].y), "+v"(wr[i].z), "+v"(wr[i].w));
      asm volatile("" : "+v"(wz[i].x), "+v"(wz[i].y), "+v"(wz[i].z), "+v"(wz[i].w));
      asm volatile("" : "+v"(wn[i].x), "+v"(wn[i].y), "+v"(wn[i].z), "+v"(wn[i].w));
    }
  }
  const float br = bhh[u], bz = bhh[HH + u], bn = bhh[2 * HH + u];
  __syncthreads();

  // xg prefetch for t=0 (only kc==0 lanes consume it)
  int p = dir ? (len - 1) : 0;
  float xr_c = 0.f, xz_c = 0.f, xn_c = 0.f;
  if (kc == 0) {
    const float* x0 = xg + ((size_t)batch * TT + p) * G3;
    xr_c = x0[u]; xz_c = x0[HH + u]; xn_c = x0[2 * HH + u];
  }

  for (int t = 0; t < len; t++) {
    // prefetch next step's xg (hidden under the FMA chain)
    float xr_n = 0.f, xz_n = 0.f, xn_n = 0.f;
    if (kc == 0 && t + 1 < len) {
      const int pnx = dir ? (len - 2 - t) : (t + 1);
      const float* xp = xg + ((size_t)batch * TT + pnx) * G3;
      xr_n = xp[u]; xz_n = xp[HH + u]; xn_n = xp[2 * HH + u];
    }
    const float hold = h_s[u];
    float ar = 0.f, az = 0.f, an = 0.f;
#pragma unroll
    for (int i = 0; i < 32; i++) {
      float4 h4 = *(const float4*)&h_s[k0 + 4 * i];
      ar += h4.x * wr[i].x + h4.y * wr[i].y + h4.z * wr[i].z + h4.w * wr[i].w;
      az += h4.x * wz[i].x + h4.y * wz[i].y + h4.z * wz[i].z + h4.w * wz[i].w;
      an += h4.x * wn[i].x + h4.y * wn[i].y + h4.z * wn[i].z + h4.w * wn[i].w;
    }
    // reduce across the 2 kc lanes (adjacent lanes, same wave)
    ar += __shfl_xor(ar, 1);
    az += __shfl_xor(az, 1);
    an += __shfl_xor(an, 1);
    __syncthreads();               // all h_s reads of this step complete

    const unsigned tag = (unsigned)((dir << 9) | (t + 1));
    if (kc == 0) {
      float r = 1.f / (1.f + expf(-(xr_c + ar + br)));
      float z = 1.f / (1.f + expf(-(xz_c + az + bz)));
      float n = tanhf(xn_c + r * (an + bn));
      float hn = (1.f - z) * n + z * hold;
      h_s[u] = hn;
      // fire-and-forget tagged store of own half (tag+data one atomic)
      unsigned long long pk =
          ((unsigned long long)tag << 32) | (unsigned long long)__float_as_uint(hn);
      __hip_atomic_store(&slots[u], pk, __ATOMIC_RELAXED, __HIP_MEMORY_SCOPE_AGENT);
      outp[((size_t)batch * TT + p) * (2 * HH) + dir * HH + u] = hn;
    }
    if (tid < 128) {               // poll own partner slot until tagged
      unsigned long long v;
      do {
        v = __hip_atomic_load(&slots[po + tid], __ATOMIC_RELAXED,
                              __HIP_MEMORY_SCOPE_AGENT);
      } while ((unsigned)(v >> 32) != tag);
      h_s[po + tid] = __uint_as_float((unsigned)v);
    }
    __syncthreads();               // h_s complete for next step
    xr_c = xr_n; xz_c = xz_n; xn_c = xn_n;
    p = dir ? (p - 1) : (p + 1);
  }
}

// ------------- scores from hmid: relu, dot w2, +b2; mask t>=len ----------
__global__ __launch_bounds__(256) void score2_kernel(
    const float* __restrict__ hmid, const float* __restrict__ w2,
    const float* __restrict__ b2, const int* __restrict__ lengths,
    float* __restrict__ scores)
{
  const int wv = threadIdx.x >> 6, lane = threadIdx.x & 63;
  const int bt = blockIdx.x * 4 + wv;
  const int b = bt >> 8, t = bt & 255;
  float v = 0.f;
  if (t < lengths[b]) {
    float hv = fmaxf(hmid[(size_t)bt * 64 + lane], 0.f);
    v = hv * w2[lane];
#pragma unroll
    for (int o = 32; o > 0; o >>= 1) v += __shfl_down(v, o);
    v += b2[0];
  }
  if (lane == 0) scores[bt] = v;
}

// -------- softmax + top-3 + normalize + seq_feat, 1 block per batch ------
__global__ __launch_bounds__(256) void attn_kernel(
    const float* __restrict__ scores, const float* __restrict__ outp,
    const float* __restrict__ temp_ptr, const int* __restrict__ lengths,
    float* __restrict__ seq_feat)
{
  const int b = blockIdx.x;
  const int t = threadIdx.x;
  const int len = lengths[b];
  float temp = fminf(fmaxf(temp_ptr[0], 0.001f), 10.0f);
  __shared__ float red[256];
  __shared__ int redi[256];
  __shared__ float topv[3]; __shared__ int topi[3];
  __shared__ float vn[3]; __shared__ float vsum_s;
  const bool valid = t < len;
  float logit = valid ? scores[b * TT + t] / temp : -INFINITY;
  red[t] = logit; __syncthreads();
  for (int s = 128; s > 0; s >>= 1) {
    if (t < s) red[t] = fmaxf(red[t], red[t + s]);
    __syncthreads();
  }
  float mx = red[0]; __syncthreads();
  float e = valid ? expf(logit - mx) : 0.f;
  red[t] = e; __syncthreads();
  for (int s = 128; s > 0; s >>= 1) {
    if (t < s) red[t] += red[t + s];
    __syncthreads();
  }
  float sum = red[0]; __syncthreads();
  float myp = e / sum;
  for (int it = 0; it < 3; it++) {
    red[t] = myp; redi[t] = t; __syncthreads();
    for (int s = 128; s > 0; s >>= 1) {
      if (t < s) {
        float v2 = red[t + s]; int i2 = redi[t + s];
        if (v2 > red[t] || (v2 == red[t] && i2 < redi[t])) { red[t] = v2; redi[t] = i2; }
      }
      __syncthreads();
    }
    if (t == 0) { topv[it] = red[0]; topi[it] = redi[0]; }
    __syncthreads();
    if (t == topi[it]) myp = -1.f;
    __syncthreads();
  }
  if (t == 0) {
    int k_act = len < 3 ? len : 3;
    float vsum = 0.f;
    for (int jj = 0; jj < 3; jj++) if (jj < k_act) vsum += topv[jj];
    vsum_s = vsum;
    float denom = fmaxf(vsum, 1e-8f);
    for (int jj = 0; jj < 3; jj++) vn[jj] = (jj < k_act) ? topv[jj] / denom : 0.f;
  }
  __syncthreads();
  if (vsum_s > 1e-8f) {
    for (int hh = t; hh < 2 * HH; hh += 256) {
      float s = 0.f;
      for (int jj = 0; jj < 3; jj++)
        s += vn[jj] * outp[((size_t)b * TT + topi[jj]) * (2 * HH) + hh];
      seq_feat[b * 2 * HH + hh] = s;
    }
  } else {
    float inv = 1.f / ((float)len + 1e-8f);
    for (int hh = t; hh < 2 * HH; hh += 256) {
      float s = 0.f;
      for (int tt2 = 0; tt2 < len; tt2++)
        s += outp[((size_t)b * TT + tt2) * (2 * HH) + hh];
      seq_feat[b * 2 * HH + hh] = s * inv;
    }
  }
}

// ------------------- final heads: (B,11) then (B,10) ---------------------
__global__ __launch_bounds__(256) void head_kernel(
    const float* __restrict__ seq_feat,
    const float* __restrict__ w_tens, const float* __restrict__ b_tens,
    const float* __restrict__ w_ones, const float* __restrict__ b_ones,
    float* __restrict__ d_out)
{
  const int b = blockIdx.x;
  const int lane = threadIdx.x & 63, wv = threadIdx.x >> 6;
  const float* sf = seq_feat + (size_t)b * 2 * HH;
  for (int o = wv; o < 21; o += 4) {
    const float* wr = (o < 11) ? (w_tens + (size_t)o * 2 * HH)
                               : (w_ones + (size_t)(o - 11) * 2 * HH);
    float s = 0.f;
    for (int e2 = lane; e2 < 2 * HH; e2 += 64) s += sf[e2] * wr[e2];
#pragma unroll
    for (int off2 = 32; off2 > 0; off2 >>= 1) s += __shfl_down(s, off2);
    if (lane == 0) {
      if (o < 11) d_out[b * 11 + o] = s + b_tens[o];
      else d_out[BB * 11 + b * 10 + (o - 11)] = s + b_ones[o - 11];
    }
  }
}

extern "C" void kernel_launch(void* const* d_in, const int* in_sizes, int n_in,
                              void* d_out, int out_size, void* d_ws, size_t ws_size,
                              hipStream_t stream)
{
  const float* feats       = (const float*)d_in[0];
  const int*   lengths     = (const int*)d_in[1];
  const float* temperature = (const float*)d_in[2];
  const float* w_ih_f = (const float*)d_in[3];
  const float* w_hh_f = (const float*)d_in[4];
  const float* b_ih_f = (const float*)d_in[5];
  const float* b_hh_f = (const float*)d_in[6];
  const float* w_ih_b = (const float*)d_in[7];
  const float* w_hh_b = (const float*)d_in[8];
  const float* b_ih_b = (const float*)d_in[9];
  const float* b_hh_b = (const float*)d_in[10];
  const float* w1 = (const float*)d_in[11];
  const float* b1 = (const float*)d_in[12];
  const float* w2 = (const float*)d_in[13];
  const float* b2 = (const float*)d_in[14];
  const float* w_tens = (const float*)d_in[15];
  const float* b_tens = (const float*)d_in[16];
  const float* w_ones = (const float*)d_in[17];
  const float* b_ones = (const float*)d_in[18];
  float* out = (float*)d_out;

  // ---- workspace layout (peak ~169 MB; xg reused per dir, tail aliased) --
  char* ws = (char*)d_ws;
  size_t off = 0;
  auto alloc = [&](size_t nbytes) {
    char* p = ws + off;
    off += nbytes;
    return p;
  };
  float* xg   = (float*)alloc((size_t)BB * TT * G3 * 4);      // 100.7 MB
  float* outp = (float*)alloc((size_t)BB * TT * 2 * HH * 4);  // 67.1 MB
  unsigned long long* Hx =
      (unsigned long long*)alloc((size_t)BB * HH * 8);        // 256 KB tagged
  float* hmid     = xg;                     // aliases (xg dead after GRUs)
  float* scores   = xg + (size_t)BB * TT * 64;
  float* seq_feat = scores + (size_t)BB * TT;

  // forward direction
  gemm_abt<<<dim3(6, 256), 256, 0, stream>>>(feats, w_ih_f, b_ih_f, xg, BB * TT, G3, DD);
  gru_pair_kernel<<<2 * BB, 256, 0, stream>>>(xg, w_hh_f, b_hh_f, lengths, outp, Hx, 0);
  // backward direction (reuses xg; tags carry dir bit, no reset needed)
  gemm_abt<<<dim3(6, 256), 256, 0, stream>>>(feats, w_ih_b, b_ih_b, xg, BB * TT, G3, DD);
  gru_pair_kernel<<<2 * BB, 256, 0, stream>>>(xg, w_hh_b, b_hh_b, lengths, outp, Hx, 1);
  // score MLP + attention + heads
  gemm_abt<<<dim3(1, 256), 256, 0, stream>>>(outp, w1, b1, hmid, BB * TT, 64, 2 * HH);
  score2_kernel<<<BB * TT / 4, 256, 0, stream>>>(hmid, w2, b2, lengths, scores);
  attn_kernel<<<BB, 256, 0, stream>>>(scores, outp, temperature, lengths, seq_feat);
  head_kernel<<<BB, 256, 0, stream>>>(seq_feat, w_tens, b_tens, w_ones, b_ones, out);
}

// Round 9
// 2113.845 us; speedup vs baseline: 3.7317x; 1.0251x over previous
//
#include <hip/hip_runtime.h>
#include <cmath>

#define BB 128
#define TT 256
#define DD 512
#define HH 256
#define G3 768   // 3*H

// ---- GEMM: C[m,n] = bias[n] + sum_k A[m,k]*W[n,k]; A (M,K), W (N,K) ------
__global__ __launch_bounds__(256) void gemm_abt(
    const float* __restrict__ A, const float* __restrict__ W,
    const float* __restrict__ bias, float* __restrict__ C,
    int M, int N, int K)
{
  __shared__ float sA[16][132];
  __shared__ float sB[16][132];
  const int tid = threadIdx.x;
  const int row0 = blockIdx.y * 128, col0 = blockIdx.x * 128;
  const int tx = tid & 15, ty = tid >> 4;
  float acc[8][8];
#pragma unroll
  for (int i = 0; i < 8; i++)
#pragma unroll
    for (int j = 0; j < 8; j++) acc[i][j] = 0.f;

  for (int k0 = 0; k0 < K; k0 += 16) {
    __syncthreads();
#pragma unroll
    for (int i = 0; i < 2; i++) {
      int q = tid + i * 256;
      int r = q >> 2, k4 = (q & 3) * 4;
      float4 av = *(const float4*)(A + (size_t)(row0 + r) * K + k0 + k4);
      sA[k4 + 0][r] = av.x; sA[k4 + 1][r] = av.y;
      sA[k4 + 2][r] = av.z; sA[k4 + 3][r] = av.w;
      float4 wv = make_float4(0.f, 0.f, 0.f, 0.f);
      if (col0 + r < N) wv = *(const float4*)(W + (size_t)(col0 + r) * K + k0 + k4);
      sB[k4 + 0][r] = wv.x; sB[k4 + 1][r] = wv.y;
      sB[k4 + 2][r] = wv.z; sB[k4 + 3][r] = wv.w;
    }
    __syncthreads();
#pragma unroll
    for (int k = 0; k < 16; k++) {
      float a0[8], b0[8];
      *(float4*)&a0[0] = *(const float4*)&sA[k][ty * 4];
      *(float4*)&a0[4] = *(const float4*)&sA[k][64 + ty * 4];
      *(float4*)&b0[0] = *(const float4*)&sB[k][tx * 4];
      *(float4*)&b0[4] = *(const float4*)&sB[k][64 + tx * 4];
#pragma unroll
      for (int i = 0; i < 8; i++)
#pragma unroll
        for (int j = 0; j < 8; j++) acc[i][j] += a0[i] * b0[j];
    }
  }
#pragma unroll
  for (int i = 0; i < 8; i++) {
    int r = row0 + ((i < 4) ? (ty * 4 + i) : (64 + ty * 4 + i - 4));
#pragma unroll
    for (int jq = 0; jq < 2; jq++) {
      int c = col0 + jq * 64 + tx * 4;
      if (c < N) {
        float4 v;
        v.x = acc[i][jq * 4 + 0] + bias[c + 0];
        v.y = acc[i][jq * 4 + 1] + bias[c + 1];
        v.z = acc[i][jq * 4 + 2] + bias[c + 2];
        v.w = acc[i][jq * 4 + 3] + bias[c + 3];
        *(float4*)(C + (size_t)r * N + c) = v;
      }
    }
  }
}

// ---- register-stationary GRU, 2 blocks per batch, TAGGED-VALUE exchange --
// r8 structure (weights asm-pinned in VGPR/AGPR, one-roundtrip tagged 64-bit
// exchange) + r9 change: BOTH directions in ONE launch (512 blocks) so bwd
// pairs BACKFILL CUs vacated by short fwd pairs (lengths ~U(1,256): each
// serial dispatch ran at ~50% average CU utilization, gated by len_max).
// Deadlock-safe: 1 block/CU; first 256 placed blocks are all fwd pairs
// (co-resident, self-contained -> guaranteed drain); bwd pairs place as CUs
// free. Pairing partner = bx^8: dispatch-adjacent (quick co-placement) and
// 8 apart = same-XCD slot under round-robin placement (locality heuristic).
// Per-dir tagged-slot arrays (Hx[dir]) prevent fwd/bwd slot livelock.
// Serial fallback (dir_arg>=0, 256 blocks) keeps r8 behavior when ws is
// too small for both xg buffers.
// Thread (ul = tid>>1, kc = tid&1): gate rows r,z,n of unit u = half*128+ul
// over k-slice [kc*128, kc*128+128) = 96 float4 = 384 pinned VGPRs.
__global__ __launch_bounds__(256, 1) void gru_pair_kernel(
    const float* __restrict__ xg_f, const float* __restrict__ xg_b,
    const float* __restrict__ whh_f, const float* __restrict__ whh_b,
    const float* __restrict__ bhh_f, const float* __restrict__ bhh_b,
    const int* __restrict__ lengths, float* __restrict__ outp,
    unsigned long long* __restrict__ Hx,   // [2][BB][HH] tagged slots
    int dir_arg)                           // -1: derive from blockIdx (fused)
{
  const int tid = threadIdx.x;
  const int bx = blockIdx.x;
  const int dir = (dir_arg >= 0) ? dir_arg : (bx >> 8);
  const int local = bx & 255;
  const int batch = ((local >> 4) << 3) | (local & 7);   // partner = local^8
  const int half = (local >> 3) & 1;
  const int ul = tid >> 1, kc = tid & 1;
  const int u = half * 128 + ul;
  const int po = (1 - half) * 128;          // partner's unit range base
  const int len = lengths[batch];
  const int k0 = kc * 128;
  const float* xg   = dir ? xg_b  : xg_f;
  const float* w_hh = dir ? whh_b : whh_f;
  const float* bhh  = dir ? bhh_b : bhh_f;
  unsigned long long* slots = Hx + ((size_t)dir * BB + batch) * HH;

  __shared__ float h_s[HH];
  if (tid < HH) h_s[tid] = 0.f;

  // one-time weight load; asm barriers pin the values in registers
  float4 wr[32], wz[32], wn[32];
  {
    const float* pr = w_hh + (size_t)u * HH + k0;
    const float* pz = w_hh + (size_t)(HH + u) * HH + k0;
    const float* pn = w_hh + (size_t)(2 * HH + u) * HH + k0;
#pragma unroll
    for (int i = 0; i < 32; i++) {
      wr[i] = *(const float4*)(pr + 4 * i);
      wz[i] = *(const float4*)(pz + 4 * i);
      wn[i] = *(const float4*)(pn + 4 * i);
    }
#pragma unroll
    for (int i = 0; i < 32; i++) {
      asm volatile("" : "+v"(wr[i].x), "+v"(wr[i].y), "+v"(wr[i].z), "+v"(wr[i].w));
      asm volatile("" : "+v"(wz[i].x), "+v"(wz[i].y), "+v"(wz[i].z), "+v"(wz[i].w));
      asm volatile("" : "+v"(wn[i].x), "+v"(wn[i].y), "+v"(wn[i].z), "+v"(wn[i].w));
    }
  }
  const float br = bhh[u], bz = bhh[HH + u], bn = bhh[2 * HH + u];
  __syncthreads();

  // xg prefetch for t=0 (only kc==0 lanes consume it)
  int p = dir ? (len - 1) : 0;
  float xr_c = 0.f, xz_c = 0.f, xn_c = 0.f;
  if (kc == 0) {
    const float* x0 = xg + ((size_t)batch * TT + p) * G3;
    xr_c = x0[u]; xz_c = x0[HH + u]; xn_c = x0[2 * HH + u];
  }

  for (int t = 0; t < len; t++) {
    // prefetch next step's xg (hidden under the FMA chain)
    float xr_n = 0.f, xz_n = 0.f, xn_n = 0.f;
    if (kc == 0 && t + 1 < len) {
      const int pnx = dir ? (len - 2 - t) : (t + 1);
      const float* xp = xg + ((size_t)batch * TT + pnx) * G3;
      xr_n = xp[u]; xz_n = xp[HH + u]; xn_n = xp[2 * HH + u];
    }
    const float hold = h_s[u];
    float ar = 0.f, az = 0.f, an = 0.f;
#pragma unroll
    for (int i = 0; i < 32; i++) {
      float4 h4 = *(const float4*)&h_s[k0 + 4 * i];
      ar += h4.x * wr[i].x + h4.y * wr[i].y + h4.z * wr[i].z + h4.w * wr[i].w;
      az += h4.x * wz[i].x + h4.y * wz[i].y + h4.z * wz[i].z + h4.w * wz[i].w;
      an += h4.x * wn[i].x + h4.y * wn[i].y + h4.z * wn[i].z + h4.w * wn[i].w;
    }
    // reduce across the 2 kc lanes (adjacent lanes, same wave)
    ar += __shfl_xor(ar, 1);
    az += __shfl_xor(az, 1);
    an += __shfl_xor(an, 1);
    __syncthreads();               // all h_s reads of this step complete

    const unsigned tag = (unsigned)((dir << 9) | (t + 1));
    if (kc == 0) {
      float r = 1.f / (1.f + expf(-(xr_c + ar + br)));
      float z = 1.f / (1.f + expf(-(xz_c + az + bz)));
      float n = tanhf(xn_c + r * (an + bn));
      float hn = (1.f - z) * n + z * hold;
      h_s[u] = hn;
      // fire-and-forget tagged store of own half (tag+data one atomic)
      unsigned long long pk =
          ((unsigned long long)tag << 32) | (unsigned long long)__float_as_uint(hn);
      __hip_atomic_store(&slots[u], pk, __ATOMIC_RELAXED, __HIP_MEMORY_SCOPE_AGENT);
      outp[((size_t)batch * TT + p) * (2 * HH) + dir * HH + u] = hn;
    }
    if (tid < 128) {               // poll own partner slot until tagged
      unsigned long long v;
      do {
        v = __hip_atomic_load(&slots[po + tid], __ATOMIC_RELAXED,
                              __HIP_MEMORY_SCOPE_AGENT);
      } while ((unsigned)(v >> 32) != tag);
      h_s[po + tid] = __uint_as_float((unsigned)v);
    }
    __syncthreads();               // h_s complete for next step
    xr_c = xr_n; xz_c = xz_n; xn_c = xn_n;
    p = dir ? (p - 1) : (p + 1);
  }
}

// ------------- scores from hmid: relu, dot w2, +b2; mask t>=len ----------
__global__ __launch_bounds__(256) void score2_kernel(
    const float* __restrict__ hmid, const float* __restrict__ w2,
    const float* __restrict__ b2, const int* __restrict__ lengths,
    float* __restrict__ scores)
{
  const int wv = threadIdx.x >> 6, lane = threadIdx.x & 63;
  const int bt = blockIdx.x * 4 + wv;
  const int b = bt >> 8, t = bt & 255;
  float v = 0.f;
  if (t < lengths[b]) {
    float hv = fmaxf(hmid[(size_t)bt * 64 + lane], 0.f);
    v = hv * w2[lane];
#pragma unroll
    for (int o = 32; o > 0; o >>= 1) v += __shfl_down(v, o);
    v += b2[0];
  }
  if (lane == 0) scores[bt] = v;
}

// -------- softmax + top-3 + normalize + seq_feat, 1 block per batch ------
__global__ __launch_bounds__(256) void attn_kernel(
    const float* __restrict__ scores, const float* __restrict__ outp,
    const float* __restrict__ temp_ptr, const int* __restrict__ lengths,
    float* __restrict__ seq_feat)
{
  const int b = blockIdx.x;
  const int t = threadIdx.x;
  const int len = lengths[b];
  float temp = fminf(fmaxf(temp_ptr[0], 0.001f), 10.0f);
  __shared__ float red[256];
  __shared__ int redi[256];
  __shared__ float topv[3]; __shared__ int topi[3];
  __shared__ float vn[3]; __shared__ float vsum_s;
  const bool valid = t < len;
  float logit = valid ? scores[b * TT + t] / temp : -INFINITY;
  red[t] = logit; __syncthreads();
  for (int s = 128; s > 0; s >>= 1) {
    if (t < s) red[t] = fmaxf(red[t], red[t + s]);
    __syncthreads();
  }
  float mx = red[0]; __syncthreads();
  float e = valid ? expf(logit - mx) : 0.f;
  red[t] = e; __syncthreads();
  for (int s = 128; s > 0; s >>= 1) {
    if (t < s) red[t] += red[t + s];
    __syncthreads();
  }
  float sum = red[0]; __syncthreads();
  float myp = e / sum;
  for (int it = 0; it < 3; it++) {
    red[t] = myp; redi[t] = t; __syncthreads();
    for (int s = 128; s > 0; s >>= 1) {
      if (t < s) {
        float v2 = red[t + s]; int i2 = redi[t + s];
        if (v2 > red[t] || (v2 == red[t] && i2 < redi[t])) { red[t] = v2; redi[t] = i2; }
      }
      __syncthreads();
    }
    if (t == 0) { topv[it] = red[0]; topi[it] = redi[0]; }
    __syncthreads();
    if (t == topi[it]) myp = -1.f;
    __syncthreads();
  }
  if (t == 0) {
    int k_act = len < 3 ? len : 3;
    float vsum = 0.f;
    for (int jj = 0; jj < 3; jj++) if (jj < k_act) vsum += topv[jj];
    vsum_s = vsum;
    float denom = fmaxf(vsum, 1e-8f);
    for (int jj = 0; jj < 3; jj++) vn[jj] = (jj < k_act) ? topv[jj] / denom : 0.f;
  }
  __syncthreads();
  if (vsum_s > 1e-8f) {
    for (int hh = t; hh < 2 * HH; hh += 256) {
      float s = 0.f;
      for (int jj = 0; jj < 3; jj++)
        s += vn[jj] * outp[((size_t)b * TT + topi[jj]) * (2 * HH) + hh];
      seq_feat[b * 2 * HH + hh] = s;
    }
  } else {
    float inv = 1.f / ((float)len + 1e-8f);
    for (int hh = t; hh < 2 * HH; hh += 256) {
      float s = 0.f;
      for (int tt2 = 0; tt2 < len; tt2++)
        s += outp[((size_t)b * TT + tt2) * (2 * HH) + hh];
      seq_feat[b * 2 * HH + hh] = s * inv;
    }
  }
}

// ------------------- final heads: (B,11) then (B,10) ---------------------
__global__ __launch_bounds__(256) void head_kernel(
    const float* __restrict__ seq_feat,
    const float* __restrict__ w_tens, const float* __restrict__ b_tens,
    const float* __restrict__ w_ones, const float* __restrict__ b_ones,
    float* __restrict__ d_out)
{
  const int b = blockIdx.x;
  const int lane = threadIdx.x & 63, wv = threadIdx.x >> 6;
  const float* sf = seq_feat + (size_t)b * 2 * HH;
  for (int o = wv; o < 21; o += 4) {
    const float* wr = (o < 11) ? (w_tens + (size_t)o * 2 * HH)
                               : (w_ones + (size_t)(o - 11) * 2 * HH);
    float s = 0.f;
    for (int e2 = lane; e2 < 2 * HH; e2 += 64) s += sf[e2] * wr[e2];
#pragma unroll
    for (int off2 = 32; off2 > 0; off2 >>= 1) s += __shfl_down(s, off2);
    if (lane == 0) {
      if (o < 11) d_out[b * 11 + o] = s + b_tens[o];
      else d_out[BB * 11 + b * 10 + (o - 11)] = s + b_ones[o - 11];
    }
  }
}

extern "C" void kernel_launch(void* const* d_in, const int* in_sizes, int n_in,
                              void* d_out, int out_size, void* d_ws, size_t ws_size,
                              hipStream_t stream)
{
  const float* feats       = (const float*)d_in[0];
  const int*   lengths     = (const int*)d_in[1];
  const float* temperature = (const float*)d_in[2];
  const float* w_ih_f = (const float*)d_in[3];
  const float* w_hh_f = (const float*)d_in[4];
  const float* b_ih_f = (const float*)d_in[5];
  const float* b_hh_f = (const float*)d_in[6];
  const float* w_ih_b = (const float*)d_in[7];
  const float* w_hh_b = (const float*)d_in[8];
  const float* b_ih_b = (const float*)d_in[9];
  const float* b_hh_b = (const float*)d_in[10];
  const float* w1 = (const float*)d_in[11];
  const float* b1 = (const float*)d_in[12];
  const float* w2 = (const float*)d_in[13];
  const float* b2 = (const float*)d_in[14];
  const float* w_tens = (const float*)d_in[15];
  const float* b_tens = (const float*)d_in[16];
  const float* w_ones = (const float*)d_in[17];
  const float* b_ones = (const float*)d_in[18];
  float* out = (float*)d_out;

  const size_t xg_sz   = (size_t)BB * TT * G3 * 4;       // 100.7 MB
  const size_t outp_sz = (size_t)BB * TT * 2 * HH * 4;   // 67.1 MB
  const size_t hx_sz   = (size_t)2 * BB * HH * 8;        // 512 KB
  const size_t fused_need = 2 * xg_sz + outp_sz + hx_sz; // ~268.9 MB
  char* ws = (char*)d_ws;

  if (ws_size >= fused_need) {
    // ---------- fused path: both xg buffers live, one 512-block GRU ------
    float* xg_f = (float*)ws;
    float* xg_b = (float*)(ws + xg_sz);
    float* outp = (float*)(ws + 2 * xg_sz);
    unsigned long long* Hx = (unsigned long long*)(ws + 2 * xg_sz + outp_sz);
    float* hmid     = xg_f;                  // aliases (xg dead after GRU)
    float* scores   = xg_f + (size_t)BB * TT * 64;
    float* seq_feat = scores + (size_t)BB * TT;

    gemm_abt<<<dim3(6, 256), 256, 0, stream>>>(feats, w_ih_f, b_ih_f, xg_f, BB * TT, G3, DD);
    gemm_abt<<<dim3(6, 256), 256, 0, stream>>>(feats, w_ih_b, b_ih_b, xg_b, BB * TT, G3, DD);
    gru_pair_kernel<<<4 * BB, 256, 0, stream>>>(
        xg_f, xg_b, w_hh_f, w_hh_b, b_hh_f, b_hh_b, lengths, outp, Hx, -1);
    gemm_abt<<<dim3(1, 256), 256, 0, stream>>>(outp, w1, b1, hmid, BB * TT, 64, 2 * HH);
    score2_kernel<<<BB * TT / 4, 256, 0, stream>>>(hmid, w2, b2, lengths, scores);
    attn_kernel<<<BB, 256, 0, stream>>>(scores, outp, temperature, lengths, seq_feat);
    head_kernel<<<BB, 256, 0, stream>>>(seq_feat, w_tens, b_tens, w_ones, b_ones, out);
  } else {
    // ---------- fallback (r8-equivalent): xg shared, two GRU launches ----
    float* xg   = (float*)ws;
    float* outp = (float*)(ws + xg_sz);
    unsigned long long* Hx = (unsigned long long*)(ws + xg_sz + outp_sz);
    float* hmid     = xg;
    float* scores   = xg + (size_t)BB * TT * 64;
    float* seq_feat = scores + (size_t)BB * TT;

    gemm_abt<<<dim3(6, 256), 256, 0, stream>>>(feats, w_ih_f, b_ih_f, xg, BB * TT, G3, DD);
    gru_pair_kernel<<<2 * BB, 256, 0, stream>>>(
        xg, xg, w_hh_f, w_hh_b, b_hh_f, b_hh_b, lengths, outp, Hx, 0);
    gemm_abt<<<dim3(6, 256), 256, 0, stream>>>(feats, w_ih_b, b_ih_b, xg, BB * TT, G3, DD);
    gru_pair_kernel<<<2 * BB, 256, 0, stream>>>(
        xg, xg, w_hh_f, w_hh_b, b_hh_f, b_hh_b, lengths, outp, Hx, 1);
    gemm_abt<<<dim3(1, 256), 256, 0, stream>>>(outp, w1, b1, hmid, BB * TT, 64, 2 * HH);
    score2_kernel<<<BB * TT / 4, 256, 0, stream>>>(hmid, w2, b2, lengths, scores);
    attn_kernel<<<BB, 256, 0, stream>>>(scores, outp, temperature, lengths, seq_feat);
    head_kernel<<<BB, 256, 0, stream>>>(seq_feat, w_tens, b_tens, w_ones, b_ones, out);
  }
}